// Round 4
// baseline (5310.612 us; speedup 1.0000x reference)
//
#include <hip/hip_runtime.h>

#define N_ATOMS 100000
#define N_EDGES 400000
#define N_MOLS  4096
#define ATOM_FDIM 133
#define BOND_FDIM 14
#define HIDDEN 300
#define DEPTH 3
#define N_LABELS 12

#define BM 64
#define BN 64
#define BK 16

typedef unsigned short bf16_t;

__device__ __forceinline__ float bf2f(bf16_t h) {
    return __uint_as_float(((unsigned int)h) << 16);
}
__device__ __forceinline__ bf16_t f2bf(float f) {
    unsigned int u = __float_as_uint(f);
    u = u + 0x7FFFu + ((u >> 16) & 1u);   // round-to-nearest-even
    return (bf16_t)(u >> 16);
}

// C = [relu]( A1@W1 + (A2? A2@W2 : 0) + (bias? bias : 0) )
// A1 dtype: bf16 if A1BF else f32. A2 always f32. C: bf16 if CBF else f32.
// All row-major; W always f32.
template<bool A1BF, bool CBF>
__global__ __launch_bounds__(256) void gemm_fused(
    const void* __restrict__ A1v, const float* __restrict__ W1, int K1,
    const float* __restrict__ A2, const float* __restrict__ W2, int K2,
    const float* __restrict__ bias, void* __restrict__ Cv,
    int M, int N, int do_relu)
{
    __shared__ __align__(16) float As[BK][BM + 4];
    __shared__ __align__(16) float Bs[BK][BN];
    const int t  = threadIdx.x;
    const int tx = t & 15;
    const int ty = t >> 4;
    const int m0 = blockIdx.x * BM;
    const int n0 = blockIdx.y * BN;

    const int lr = t >> 2;            // A-tile row 0..63
    const int lk = (t & 3) * 4;       // A-tile k offset 0,4,8,12
    const int bk = t >> 4;            // B-tile k 0..15
    const int bn = (t & 15) * 4;      // B-tile n 0..60

    float acc[4][4] = {};

    for (int phase = 0; phase < 2; ++phase) {
        const bool isA1 = (phase == 0);
        if (isA1 ? (A1v == nullptr) : (A2 == nullptr)) continue;
        const float* __restrict__ W = isA1 ? W1 : W2;
        const int K = isA1 ? K1 : K2;
        const bool k4 = ((K & 3) == 0);

        for (int k0 = 0; k0 < K; k0 += BK) {
            // ---- stage A tile (transposed into As[k][m]) ----
            {
                const int row = m0 + lr;
                const int kbase = k0 + lk;
                float v0 = 0.f, v1 = 0.f, v2 = 0.f, v3 = 0.f;
                if (row < M) {
                    if (isA1 && A1BF) {
                        const bf16_t* ap = (const bf16_t*)A1v + (size_t)row * K;
                        if (k4 && (kbase + 3 < K)) {
                            ushort4 u = *reinterpret_cast<const ushort4*>(ap + kbase); // 8B aligned
                            v0 = bf2f(u.x); v1 = bf2f(u.y); v2 = bf2f(u.z); v3 = bf2f(u.w);
                        } else {
                            if (kbase + 0 < K) v0 = bf2f(ap[kbase + 0]);
                            if (kbase + 1 < K) v1 = bf2f(ap[kbase + 1]);
                            if (kbase + 2 < K) v2 = bf2f(ap[kbase + 2]);
                            if (kbase + 3 < K) v3 = bf2f(ap[kbase + 3]);
                        }
                    } else {
                        const float* ap = isA1 ? (const float*)A1v + (size_t)row * K
                                               : A2 + (size_t)row * K;
                        if (k4 && (kbase + 3 < K)) {
                            float4 v = *reinterpret_cast<const float4*>(ap + kbase);
                            v0 = v.x; v1 = v.y; v2 = v.z; v3 = v.w;
                        } else {
                            if (kbase + 0 < K) v0 = ap[kbase + 0];
                            if (kbase + 1 < K) v1 = ap[kbase + 1];
                            if (kbase + 2 < K) v2 = ap[kbase + 2];
                            if (kbase + 3 < K) v3 = ap[kbase + 3];
                        }
                    }
                }
                As[lk + 0][lr] = v0;
                As[lk + 1][lr] = v1;
                As[lk + 2][lr] = v2;
                As[lk + 3][lr] = v3;
            }
            // ---- stage B tile ----
            {
                const int kk = k0 + bk;
                float v0 = 0.f, v1 = 0.f, v2 = 0.f, v3 = 0.f;
                if (kk < K) {
                    const int nbase = n0 + bn;
                    if (nbase + 3 < N) {
                        float4 v = *reinterpret_cast<const float4*>(W + (size_t)kk * N + nbase);
                        v0 = v.x; v1 = v.y; v2 = v.z; v3 = v.w;
                    } else {
                        const float* wp = W + (size_t)kk * N;
                        if (nbase + 0 < N) v0 = wp[nbase + 0];
                        if (nbase + 1 < N) v1 = wp[nbase + 1];
                        if (nbase + 2 < N) v2 = wp[nbase + 2];
                        if (nbase + 3 < N) v3 = wp[nbase + 3];
                    }
                }
                Bs[bk][bn + 0] = v0;
                Bs[bk][bn + 1] = v1;
                Bs[bk][bn + 2] = v2;
                Bs[bk][bn + 3] = v3;
            }
            __syncthreads();
            #pragma unroll
            for (int k = 0; k < BK; ++k) {
                float4 a = *reinterpret_cast<const float4*>(&As[k][ty * 4]);
                float4 b = *reinterpret_cast<const float4*>(&Bs[k][tx * 4]);
                float av[4] = {a.x, a.y, a.z, a.w};
                float bv[4] = {b.x, b.y, b.z, b.w};
                #pragma unroll
                for (int i = 0; i < 4; ++i)
                    #pragma unroll
                    for (int j = 0; j < 4; ++j)
                        acc[i][j] = fmaf(av[i], bv[j], acc[i][j]);
            }
            __syncthreads();
        }
    }

    #pragma unroll
    for (int i = 0; i < 4; ++i) {
        const int row = m0 + ty * 4 + i;
        if (row >= M) continue;
        #pragma unroll
        for (int j = 0; j < 4; ++j) {
            const int col = n0 + tx * 4 + j;
            if (col >= N) continue;
            float v = acc[i][j];
            if (bias) v += bias[col];
            if (do_relu) v = fmaxf(v, 0.f);
            if (CBF) ((bf16_t*)Cv)[(size_t)row * N + col] = f2bf(v);
            else     ((float*)Cv)[(size_t)row * N + col] = v;
        }
    }
}

// agg[dst[e]] += relu(hW[src[e]] + edge_attr[e] @ WiB); hW in bf16, agg fp32.
#define EDGES_PER_BLOCK 64
__global__ __launch_bounds__(256) void edge_scatter(
    const bf16_t* __restrict__ hW, const float* __restrict__ edge_attr,
    const int* __restrict__ src, const int* __restrict__ dst,
    const float* __restrict__ WiB, float* __restrict__ agg, int n_edges)
{
    __shared__ __align__(16) float sWiB[BOND_FDIM * HIDDEN];   // 16.8 KB
    __shared__ __align__(16) float sEA[EDGES_PER_BLOCK][BOND_FDIM];
    __shared__ int   sSrc[EDGES_PER_BLOCK];
    __shared__ int   sDst[EDGES_PER_BLOCK];

    const int t = threadIdx.x;
    for (int i = t; i < BOND_FDIM * HIDDEN; i += 256) sWiB[i] = WiB[i];

    const int e0 = blockIdx.x * EDGES_PER_BLOCK;
    const int ne = min(EDGES_PER_BLOCK, n_edges - e0);
    for (int i = t; i < ne * BOND_FDIM; i += 256)
        sEA[i / BOND_FDIM][i % BOND_FDIM] = edge_attr[(size_t)e0 * BOND_FDIM + i];
    if (t < ne) { sSrc[t] = src[e0 + t]; sDst[t] = dst[e0 + t]; }
    __syncthreads();

    const int half = t >> 7;          // 0/1: which edge of a pair
    const int tj   = t & 127;
    for (int e = half; e < ne; e += 2) {
        const int s = sSrc[e];
        const int d = sDst[e];
        const bf16_t* __restrict__ hrow = hW + (size_t)s * HIDDEN;
        float* __restrict__ arow = agg + (size_t)d * HIDDEN;
        float ea[BOND_FDIM];
        #pragma unroll
        for (int k = 0; k < BOND_FDIM; ++k) ea[k] = sEA[e][k];
        for (int jp = tj; jp < HIDDEN / 2; jp += 128) {       // 150 bf16 pairs
            ushort2 h2 = *reinterpret_cast<const ushort2*>(hrow + 2 * jp); // 4B aligned
            float v0 = bf2f(h2.x), v1 = bf2f(h2.y);
            #pragma unroll
            for (int k = 0; k < BOND_FDIM; ++k) {
                v0 = fmaf(ea[k], sWiB[k * HIDDEN + 2 * jp + 0], v0);
                v1 = fmaf(ea[k], sWiB[k * HIDDEN + 2 * jp + 1], v1);
            }
            atomicAdd(&arow[2 * jp + 0], fmaxf(v0, 0.f));
            atomicAdd(&arow[2 * jp + 1], fmaxf(v1, 0.f));
        }
    }
}

// Segment-sum of bf16 h_v into fp32 mol_repr (batch sorted): run-length regs,
// atomics only on segment boundaries.
#define ATOMS_PER_BLOCK 32
__global__ __launch_bounds__(320) void mol_reduce(
    const bf16_t* __restrict__ hv, const int* __restrict__ batch,
    float* __restrict__ mol, int n_atoms)
{
    const int j = threadIdx.x;
    if (j >= HIDDEN) return;
    const int a0 = blockIdx.x * ATOMS_PER_BLOCK;
    const int aend = min(a0 + ATOMS_PER_BLOCK, n_atoms);
    float acc = 0.f;
    int cur = batch[a0];
    for (int a = a0; a < aend; ++a) {
        const int b = batch[a];
        if (b != cur) {
            atomicAdd(&mol[(size_t)cur * HIDDEN + j], acc);
            acc = 0.f;
            cur = b;
        }
        acc += bf2f(hv[(size_t)a * HIDDEN + j]);
    }
    atomicAdd(&mol[(size_t)cur * HIDDEN + j], acc);
}

__global__ void fill_const(float* p, int n, float v) {
    int i = blockIdx.x * blockDim.x + threadIdx.x;
    if (i < n) p[i] = v;
}

static inline size_t align256(size_t x) { return (x + 255) & ~(size_t)255; }

extern "C" void kernel_launch(void* const* d_in, const int* in_sizes, int n_in,
                              void* d_out, int out_size, void* d_ws, size_t ws_size,
                              hipStream_t stream) {
    const float* x       = (const float*)d_in[0];
    const int*   ei      = (const int*)  d_in[1];
    const float* ea      = (const float*)d_in[2];
    const int*   batch   = (const int*)  d_in[3];
    const float* atom_W  = (const float*)d_in[4];
    const float* atom_b  = (const float*)d_in[5];
    // d_in[6] bond_W, d_in[7] bond_b, d_in[9] Wh: dead code (h_e never reaches output)
    const float* Wi      = (const float*)d_in[8];    // [314,300]
    const float* Wo      = (const float*)d_in[10];   // [600,300]
    const float* Wo_b    = (const float*)d_in[11];
    const float* f1W     = (const float*)d_in[12];
    const float* f1b     = (const float*)d_in[13];
    const float* f2W     = (const float*)d_in[14];
    const float* f2b     = (const float*)d_in[15];

    const int* src = ei;            // edge_index[0]
    const int* dst = ei + N_EDGES;  // edge_index[1]

    const float* Wi_top = Wi;                            // [300,300]
    const float* WiB    = Wi + (size_t)HIDDEN * HIDDEN;  // [14,300]
    const float* Wo_top = Wo;                            // [300,300]
    const float* Wo_bot = Wo + (size_t)HIDDEN * HIDDEN;  // [300,300]

    // ---- workspace: hv ping/pong in bf16 (60MB ea), agg fp32 (120MB) ----
    const size_t hv_bf  = (size_t)N_ATOMS * HIDDEN * sizeof(bf16_t);  // 60 MB
    const size_t agg_f  = (size_t)N_ATOMS * HIDDEN * sizeof(float);   // 120 MB
    const size_t mol_f  = (size_t)N_MOLS  * HIDDEN * sizeof(float);   // 4.9 MB
    const size_t needed = 2 * align256(hv_bf) + align256(agg_f) + 2 * align256(mol_f);
    if (ws_size < needed) {
        // Canary: distinguish "workspace too small" (err ~1e6 next round)
        // from a genuine compute bug (err ~0.2).
        fill_const<<<dim3((out_size + 255) / 256), dim3(256), 0, stream>>>(
            (float*)d_out, out_size, 1.0e6f);
        return;
    }
    char* p = (char*)d_ws;
    bf16_t* bufA = (bf16_t*)p; p += align256(hv_bf);   // hv ping
    bf16_t* bufB = (bf16_t*)p; p += align256(hv_bf);   // hW / hv_out (aliased)
    float*  agg  = (float*)p;  p += align256(agg_f);
    float*  mol  = (float*)p;  p += align256(mol_f);
    float*  ffnh = (float*)p;  p += align256(mol_f);

    dim3 blk(256);
    dim3 gA((N_ATOMS + BM - 1) / BM, (HIDDEN + BN - 1) / BN);   // 1563 x 5
    dim3 gM((N_MOLS + BM - 1) / BM, (HIDDEN + BN - 1) / BN);    // 64 x 5
    dim3 gO((N_MOLS + BM - 1) / BM, (N_LABELS + BN - 1) / BN);  // 64 x 1

    // 1) h_v = relu(x @ atom_W + atom_b)            [f32 in, bf16 out]
    gemm_fused<false, true><<<gA, blk, 0, stream>>>(
        x, atom_W, ATOM_FDIM, nullptr, nullptr, 0, atom_b, bufA, N_ATOMS, HIDDEN, 1);

    bf16_t* hv_in   = bufA;
    bf16_t* scratch = bufB;   // holds hW, then hv_out
    for (int it = 0; it < DEPTH; ++it) {
        // 2a) hW = h_v @ Wi_top                     [bf16 in, bf16 out, no relu]
        gemm_fused<true, true><<<gA, blk, 0, stream>>>(
            hv_in, Wi_top, HIDDEN, nullptr, nullptr, 0, nullptr, scratch, N_ATOMS, HIDDEN, 0);
        // 2b) agg = scatter_add(relu(hW[src] + ea@WiB), dst)
        hipMemsetAsync(agg, 0, agg_f, stream);
        edge_scatter<<<dim3((N_EDGES + EDGES_PER_BLOCK - 1) / EDGES_PER_BLOCK), blk, 0, stream>>>(
            scratch, ea, src, dst, WiB, agg, N_EDGES);
        // 2c) h_v' = relu(h_v @ Wo_top + agg @ Wo_bot + Wo_b)   (hW dead -> reuse)
        gemm_fused<true, true><<<gA, blk, 0, stream>>>(
            hv_in, Wo_top, HIDDEN, agg, Wo_bot, HIDDEN, Wo_b, scratch, N_ATOMS, HIDDEN, 1);
        bf16_t* tmp = hv_in; hv_in = scratch; scratch = tmp;
    }

    // 3) mol_repr = segment_sum(h_v, batch)
    hipMemsetAsync(mol, 0, mol_f, stream);
    mol_reduce<<<dim3((N_ATOMS + ATOMS_PER_BLOCK - 1) / ATOMS_PER_BLOCK), dim3(320), 0, stream>>>(
        hv_in, batch, mol, N_ATOMS);

    // 4) ffn                                        [f32 all the way]
    gemm_fused<false, false><<<gM, blk, 0, stream>>>(
        mol, f1W, HIDDEN, nullptr, nullptr, 0, f1b, ffnh, N_MOLS, HIDDEN, 1);
    gemm_fused<false, false><<<gO, blk, 0, stream>>>(
        ffnh, f2W, HIDDEN, nullptr, nullptr, 0, f2b, (float*)d_out, N_MOLS, N_LABELS, 0);
}

// Round 5
// 3655.795 us; speedup vs baseline: 1.4527x; 1.4527x over previous
//
#include <hip/hip_runtime.h>

#define N_ATOMS 100000
#define N_EDGES 400000
#define N_MOLS  4096
#define ATOM_FDIM 133
#define BOND_FDIM 14
#define HIDDEN 300
#define DEPTH 3
#define N_LABELS 12

#define BM 64
#define BN 64
#define BK 16

typedef unsigned short bf16_t;

__device__ __forceinline__ float bf2f(bf16_t h) {
    return __uint_as_float(((unsigned int)h) << 16);
}
__device__ __forceinline__ bf16_t f2bf(float f) {
    unsigned int u = __float_as_uint(f);
    u = u + 0x7FFFu + ((u >> 16) & 1u);   // round-to-nearest-even
    return (bf16_t)(u >> 16);
}

// C = [relu]( A1@W1 + (A2? A2@W2 : 0) + (bias? bias : 0) )
// A1 dtype: bf16 if A1BF else f32. A2 always f32. C: bf16 if CBF else f32.
template<bool A1BF, bool CBF>
__global__ __launch_bounds__(256) void gemm_fused(
    const void* __restrict__ A1v, const float* __restrict__ W1, int K1,
    const float* __restrict__ A2, const float* __restrict__ W2, int K2,
    const float* __restrict__ bias, void* __restrict__ Cv,
    int M, int N, int do_relu)
{
    __shared__ __align__(16) float As[BK][BM + 4];
    __shared__ __align__(16) float Bs[BK][BN];
    const int t  = threadIdx.x;
    const int tx = t & 15;
    const int ty = t >> 4;
    const int m0 = blockIdx.x * BM;
    const int n0 = blockIdx.y * BN;

    const int lr = t >> 2;            // A-tile row 0..63
    const int lk = (t & 3) * 4;       // A-tile k offset 0,4,8,12
    const int bk = t >> 4;            // B-tile k 0..15
    const int bn = (t & 15) * 4;      // B-tile n 0..60

    float acc[4][4] = {};

    for (int phase = 0; phase < 2; ++phase) {
        const bool isA1 = (phase == 0);
        if (isA1 ? (A1v == nullptr) : (A2 == nullptr)) continue;
        const float* __restrict__ W = isA1 ? W1 : W2;
        const int K = isA1 ? K1 : K2;
        const bool k4 = ((K & 3) == 0);

        for (int k0 = 0; k0 < K; k0 += BK) {
            {
                const int row = m0 + lr;
                const int kbase = k0 + lk;
                float v0 = 0.f, v1 = 0.f, v2 = 0.f, v3 = 0.f;
                if (row < M) {
                    if (isA1 && A1BF) {
                        const bf16_t* ap = (const bf16_t*)A1v + (size_t)row * K;
                        if (k4 && (kbase + 3 < K)) {
                            ushort4 u = *reinterpret_cast<const ushort4*>(ap + kbase);
                            v0 = bf2f(u.x); v1 = bf2f(u.y); v2 = bf2f(u.z); v3 = bf2f(u.w);
                        } else {
                            if (kbase + 0 < K) v0 = bf2f(ap[kbase + 0]);
                            if (kbase + 1 < K) v1 = bf2f(ap[kbase + 1]);
                            if (kbase + 2 < K) v2 = bf2f(ap[kbase + 2]);
                            if (kbase + 3 < K) v3 = bf2f(ap[kbase + 3]);
                        }
                    } else {
                        const float* ap = isA1 ? (const float*)A1v + (size_t)row * K
                                               : A2 + (size_t)row * K;
                        if (k4 && (kbase + 3 < K)) {
                            float4 v = *reinterpret_cast<const float4*>(ap + kbase);
                            v0 = v.x; v1 = v.y; v2 = v.z; v3 = v.w;
                        } else {
                            if (kbase + 0 < K) v0 = ap[kbase + 0];
                            if (kbase + 1 < K) v1 = ap[kbase + 1];
                            if (kbase + 2 < K) v2 = ap[kbase + 2];
                            if (kbase + 3 < K) v3 = ap[kbase + 3];
                        }
                    }
                }
                As[lk + 0][lr] = v0;
                As[lk + 1][lr] = v1;
                As[lk + 2][lr] = v2;
                As[lk + 3][lr] = v3;
            }
            {
                const int kk = k0 + bk;
                float v0 = 0.f, v1 = 0.f, v2 = 0.f, v3 = 0.f;
                if (kk < K) {
                    const int nbase = n0 + bn;
                    if (nbase + 3 < N) {
                        float4 v = *reinterpret_cast<const float4*>(W + (size_t)kk * N + nbase);
                        v0 = v.x; v1 = v.y; v2 = v.z; v3 = v.w;
                    } else {
                        const float* wp = W + (size_t)kk * N;
                        if (nbase + 0 < N) v0 = wp[nbase + 0];
                        if (nbase + 1 < N) v1 = wp[nbase + 1];
                        if (nbase + 2 < N) v2 = wp[nbase + 2];
                        if (nbase + 3 < N) v3 = wp[nbase + 3];
                    }
                }
                Bs[bk][bn + 0] = v0;
                Bs[bk][bn + 1] = v1;
                Bs[bk][bn + 2] = v2;
                Bs[bk][bn + 3] = v3;
            }
            __syncthreads();
            #pragma unroll
            for (int k = 0; k < BK; ++k) {
                float4 a = *reinterpret_cast<const float4*>(&As[k][ty * 4]);
                float4 b = *reinterpret_cast<const float4*>(&Bs[k][tx * 4]);
                float av[4] = {a.x, a.y, a.z, a.w};
                float bv[4] = {b.x, b.y, b.z, b.w};
                #pragma unroll
                for (int i = 0; i < 4; ++i)
                    #pragma unroll
                    for (int j = 0; j < 4; ++j)
                        acc[i][j] = fmaf(av[i], bv[j], acc[i][j]);
            }
            __syncthreads();
        }
    }

    #pragma unroll
    for (int i = 0; i < 4; ++i) {
        const int row = m0 + ty * 4 + i;
        if (row >= M) continue;
        #pragma unroll
        for (int j = 0; j < 4; ++j) {
            const int col = n0 + tx * 4 + j;
            if (col >= N) continue;
            float v = acc[i][j];
            if (bias) v += bias[col];
            if (do_relu) v = fmaxf(v, 0.f);
            if (CBF) ((bf16_t*)Cv)[(size_t)row * N + col] = f2bf(v);
            else     ((float*)Cv)[(size_t)row * N + col] = v;
        }
    }
}

// ---------------- CSR build over dst (constant within a call) ----------------
__global__ void csr_hist(const int* __restrict__ dst, int* __restrict__ cnt, int n) {
    int i = blockIdx.x * blockDim.x + threadIdx.x;
    if (i < n) atomicAdd(&cnt[dst[i]], 1);
}

#define SCAN_T 1024
__global__ __launch_bounds__(SCAN_T) void csr_scan(
    const int* __restrict__ cnt, int* __restrict__ row_ptr) {
    __shared__ int sums[SCAN_T];
    const int t = threadIdx.x;
    const int per = (N_ATOMS + SCAN_T - 1) / SCAN_T;   // 98
    const int base = t * per;
    int local = 0;
    for (int i = 0; i < per; ++i) {
        int idx = base + i;
        if (idx < N_ATOMS) local += cnt[idx];
    }
    sums[t] = local;
    __syncthreads();
    // Hillis-Steele inclusive scan over thread totals
    for (int off = 1; off < SCAN_T; off <<= 1) {
        int v = (t >= off) ? sums[t - off] : 0;
        __syncthreads();
        if (t >= off) sums[t] += v;
        __syncthreads();
    }
    int prefix = (t == 0) ? 0 : sums[t - 1];   // exclusive base for this thread
    for (int i = 0; i < per; ++i) {
        int idx = base + i;
        if (idx < N_ATOMS) {
            row_ptr[idx] = prefix;
            prefix += cnt[idx];
        }
    }
    if (t == SCAN_T - 1) row_ptr[N_ATOMS] = prefix;    // total edges
}

__global__ void csr_fill(const int* __restrict__ dst, int* __restrict__ pos,
                         int* __restrict__ eid, int n) {
    int i = blockIdx.x * blockDim.x + threadIdx.x;
    if (i < n) {
        int p = atomicAdd(&pos[dst[i]], 1);
        eid[p] = i;
    }
}

// ---- agg[v] = sum over incoming edges e of relu(hW[src_e] + ea_e @ WiB) ----
// One 64-lane wave per atom; lane l owns cols {l, l+64, ..}. No atomics,
// single streaming write per row. ea/eid/src are wave-uniform -> scalar loads.
__global__ __launch_bounds__(256) void gather_agg(
    const bf16_t* __restrict__ hW, const float* __restrict__ edge_attr,
    const int* __restrict__ src, const int* __restrict__ row_ptr,
    const int* __restrict__ eid, const float* __restrict__ WiB,
    float* __restrict__ agg)
{
    __shared__ __align__(16) float sWiB[BOND_FDIM * HIDDEN];   // 16.8 KB
    const int t = threadIdx.x;
    for (int i = t; i < BOND_FDIM * HIDDEN; i += 256) sWiB[i] = WiB[i];
    __syncthreads();

    const int wave = t >> 6;
    const int lane = t & 63;
    const int v = blockIdx.x * 4 + wave;
    if (v >= N_ATOMS) return;
    const int beg = row_ptr[v];
    const int end = row_ptr[v + 1];

    float acc[5] = {0.f, 0.f, 0.f, 0.f, 0.f};
    for (int idx = beg; idx < end; ++idx) {
        const int e = eid[idx];
        const int s = src[e];
        float eav[BOND_FDIM];
        #pragma unroll
        for (int k = 0; k < BOND_FDIM; ++k)
            eav[k] = edge_attr[(size_t)e * BOND_FDIM + k];
        const bf16_t* __restrict__ hrow = hW + (size_t)s * HIDDEN;
        #pragma unroll
        for (int c = 0; c < 5; ++c) {
            const int j = lane + 64 * c;
            if (j < HIDDEN) {
                float m = bf2f(hrow[j]);
                #pragma unroll
                for (int k = 0; k < BOND_FDIM; ++k)
                    m = fmaf(eav[k], sWiB[k * HIDDEN + j], m);
                acc[c] += fmaxf(m, 0.f);
            }
        }
    }
    float* __restrict__ arow = agg + (size_t)v * HIDDEN;
    #pragma unroll
    for (int c = 0; c < 5; ++c) {
        const int j = lane + 64 * c;
        if (j < HIDDEN) arow[j] = acc[c];
    }
}

// Segment-sum of bf16 h_v into fp32 mol_repr (batch sorted).
#define ATOMS_PER_BLOCK 32
__global__ __launch_bounds__(320) void mol_reduce(
    const bf16_t* __restrict__ hv, const int* __restrict__ batch,
    float* __restrict__ mol, int n_atoms)
{
    const int j = threadIdx.x;
    if (j >= HIDDEN) return;
    const int a0 = blockIdx.x * ATOMS_PER_BLOCK;
    const int aend = min(a0 + ATOMS_PER_BLOCK, n_atoms);
    float acc = 0.f;
    int cur = batch[a0];
    for (int a = a0; a < aend; ++a) {
        const int b = batch[a];
        if (b != cur) {
            atomicAdd(&mol[(size_t)cur * HIDDEN + j], acc);
            acc = 0.f;
            cur = b;
        }
        acc += bf2f(hv[(size_t)a * HIDDEN + j]);
    }
    atomicAdd(&mol[(size_t)cur * HIDDEN + j], acc);
}

__global__ void fill_const(float* p, int n, float v) {
    int i = blockIdx.x * blockDim.x + threadIdx.x;
    if (i < n) p[i] = v;
}

static inline size_t align256(size_t x) { return (x + 255) & ~(size_t)255; }

extern "C" void kernel_launch(void* const* d_in, const int* in_sizes, int n_in,
                              void* d_out, int out_size, void* d_ws, size_t ws_size,
                              hipStream_t stream) {
    const float* x       = (const float*)d_in[0];
    const int*   ei      = (const int*)  d_in[1];
    const float* ea      = (const float*)d_in[2];
    const int*   batch   = (const int*)  d_in[3];
    const float* atom_W  = (const float*)d_in[4];
    const float* atom_b  = (const float*)d_in[5];
    // d_in[6] bond_W, d_in[7] bond_b, d_in[9] Wh: dead code
    const float* Wi      = (const float*)d_in[8];    // [314,300]
    const float* Wo      = (const float*)d_in[10];   // [600,300]
    const float* Wo_b    = (const float*)d_in[11];
    const float* f1W     = (const float*)d_in[12];
    const float* f1b     = (const float*)d_in[13];
    const float* f2W     = (const float*)d_in[14];
    const float* f2b     = (const float*)d_in[15];

    const int* src = ei;            // edge_index[0]
    const int* dst = ei + N_EDGES;  // edge_index[1]

    const float* Wi_top = Wi;                            // [300,300]
    const float* WiB    = Wi + (size_t)HIDDEN * HIDDEN;  // [14,300]
    const float* Wo_top = Wo;                            // [300,300]
    const float* Wo_bot = Wo + (size_t)HIDDEN * HIDDEN;  // [300,300]

    // ---- workspace ----
    const size_t hv_bf  = (size_t)N_ATOMS * HIDDEN * sizeof(bf16_t);  // 60 MB
    const size_t agg_f  = (size_t)N_ATOMS * HIDDEN * sizeof(float);   // 120 MB
    const size_t mol_f  = (size_t)N_MOLS  * HIDDEN * sizeof(float);   // 4.9 MB
    const size_t rp_b   = (size_t)(N_ATOMS + 1) * sizeof(int);
    const size_t cnt_b  = (size_t)N_ATOMS * sizeof(int);
    const size_t eid_b  = (size_t)N_EDGES * sizeof(int);
    const size_t needed = 2 * align256(hv_bf) + align256(agg_f) + 2 * align256(mol_f)
                        + align256(rp_b) + align256(cnt_b) + align256(eid_b);
    if (ws_size < needed) {
        fill_const<<<dim3((out_size + 255) / 256), dim3(256), 0, stream>>>(
            (float*)d_out, out_size, 1.0e6f);   // canary: ws too small
        return;
    }
    char* p = (char*)d_ws;
    bf16_t* bufA   = (bf16_t*)p; p += align256(hv_bf);   // hv ping
    bf16_t* bufB   = (bf16_t*)p; p += align256(hv_bf);   // hW / hv_out (aliased)
    float*  agg    = (float*)p;  p += align256(agg_f);
    float*  mol    = (float*)p;  p += align256(mol_f);
    float*  ffnh   = (float*)p;  p += align256(mol_f);
    int*    row_ptr= (int*)p;    p += align256(rp_b);
    int*    cntpos = (int*)p;    p += align256(cnt_b);   // histogram, then fill-cursor
    int*    eid    = (int*)p;    p += align256(eid_b);

    dim3 blk(256);
    dim3 gA((N_ATOMS + BM - 1) / BM, (HIDDEN + BN - 1) / BN);   // 1563 x 5
    dim3 gM((N_MOLS + BM - 1) / BM, (HIDDEN + BN - 1) / BN);    // 64 x 5
    dim3 gO((N_MOLS + BM - 1) / BM, (N_LABELS + BN - 1) / BN);  // 64 x 1
    dim3 gE((N_EDGES + 255) / 256);

    // ---- CSR over dst (once per call; reused by all 3 iterations) ----
    hipMemsetAsync(cntpos, 0, cnt_b, stream);
    csr_hist<<<gE, blk, 0, stream>>>(dst, cntpos, N_EDGES);
    csr_scan<<<dim3(1), dim3(SCAN_T), 0, stream>>>(cntpos, row_ptr);
    hipMemcpyAsync(cntpos, row_ptr, cnt_b, hipMemcpyDeviceToDevice, stream);
    csr_fill<<<gE, blk, 0, stream>>>(dst, cntpos, eid, N_EDGES);

    // 1) h_v = relu(x @ atom_W + atom_b)            [f32 in, bf16 out]
    gemm_fused<false, true><<<gA, blk, 0, stream>>>(
        x, atom_W, ATOM_FDIM, nullptr, nullptr, 0, atom_b, bufA, N_ATOMS, HIDDEN, 1);

    bf16_t* hv_in   = bufA;
    bf16_t* scratch = bufB;   // holds hW, then hv_out
    for (int it = 0; it < DEPTH; ++it) {
        // 2a) hW = h_v @ Wi_top                     [bf16 in, bf16 out, no relu]
        gemm_fused<true, true><<<gA, blk, 0, stream>>>(
            hv_in, Wi_top, HIDDEN, nullptr, nullptr, 0, nullptr, scratch, N_ATOMS, HIDDEN, 0);
        // 2b) agg = CSR-gather of relu(hW[src] + ea@WiB) over incoming edges
        gather_agg<<<dim3((N_ATOMS + 3) / 4), blk, 0, stream>>>(
            scratch, ea, src, row_ptr, eid, WiB, agg);
        // 2c) h_v' = relu(h_v @ Wo_top + agg @ Wo_bot + Wo_b)   (hW dead -> reuse)
        gemm_fused<true, true><<<gA, blk, 0, stream>>>(
            hv_in, Wo_top, HIDDEN, agg, Wo_bot, HIDDEN, Wo_b, scratch, N_ATOMS, HIDDEN, 1);
        bf16_t* tmp = hv_in; hv_in = scratch; scratch = tmp;
    }

    // 3) mol_repr = segment_sum(h_v, batch)
    hipMemsetAsync(mol, 0, mol_f, stream);
    mol_reduce<<<dim3((N_ATOMS + ATOMS_PER_BLOCK - 1) / ATOMS_PER_BLOCK), dim3(320), 0, stream>>>(
        hv_in, batch, mol, N_ATOMS);

    // 4) ffn                                        [f32 all the way]
    gemm_fused<false, false><<<gM, blk, 0, stream>>>(
        mol, f1W, HIDDEN, nullptr, nullptr, 0, f1b, ffnh, N_MOLS, HIDDEN, 1);
    gemm_fused<false, false><<<gO, blk, 0, stream>>>(
        ffnh, f2W, HIDDEN, nullptr, nullptr, 0, f2b, (float*)d_out, N_MOLS, N_LABELS, 0);
}

// Round 7
// 1889.609 us; speedup vs baseline: 2.8104x; 1.9347x over previous
//
#include <hip/hip_runtime.h>

#define N_ATOMS 100000
#define N_EDGES 400000
#define N_MOLS  4096
#define ATOM_FDIM 133
#define BOND_FDIM 14
#define HIDDEN 300
#define DEPTH 3
#define N_LABELS 12

#define KPAD 320          // padded K/row-stride for bf16 activation buffers
#define WT_LD 320         // Wt leading dim (k-dim), padded

#define BM 64
#define BN 64
#define BK 16

typedef unsigned short bf16_t;
typedef __bf16 bf16x8_t __attribute__((ext_vector_type(8)));
typedef float f32x4_t __attribute__((ext_vector_type(4)));

__device__ __forceinline__ float bf2f(bf16_t h) {
    return __uint_as_float(((unsigned int)h) << 16);
}
__device__ __forceinline__ bf16_t f2bf(float f) {
    unsigned int u = __float_as_uint(f);
    u = u + 0x7FFFu + ((u >> 16) & 1u);   // round-to-nearest-even
    return (bf16_t)(u >> 16);
}

// ---------------- scalar GEMM (atom embed + ffn only) ----------------
// C = [relu](A1@W1 + bias). A1 f32 [M,K] lda=K; W f32 [K,N]; C bf16(ldc) or f32(ldc).
template<bool CBF>
__global__ __launch_bounds__(256) void gemm_fused(
    const float* __restrict__ A1, const float* __restrict__ W1, int K1,
    const float* __restrict__ bias, void* __restrict__ Cv,
    int M, int N, int ldc, int do_relu)
{
    __shared__ __align__(16) float As[BK][BM + 4];
    __shared__ __align__(16) float Bs[BK][BN];
    const int t  = threadIdx.x;
    const int tx = t & 15;
    const int ty = t >> 4;
    const int m0 = blockIdx.x * BM;
    const int n0 = blockIdx.y * BN;

    const int lr = t >> 2;
    const int lk = (t & 3) * 4;
    const int bk = t >> 4;
    const int bn = (t & 15) * 4;

    float acc[4][4] = {};
    const int K = K1;
    const bool k4 = ((K & 3) == 0);

    for (int k0 = 0; k0 < K; k0 += BK) {
        {
            const int row = m0 + lr;
            const int kbase = k0 + lk;
            float v0 = 0.f, v1 = 0.f, v2 = 0.f, v3 = 0.f;
            if (row < M) {
                const float* ap = A1 + (size_t)row * K;
                if (k4 && (kbase + 3 < K)) {
                    float4 v = *reinterpret_cast<const float4*>(ap + kbase);
                    v0 = v.x; v1 = v.y; v2 = v.z; v3 = v.w;
                } else {
                    if (kbase + 0 < K) v0 = ap[kbase + 0];
                    if (kbase + 1 < K) v1 = ap[kbase + 1];
                    if (kbase + 2 < K) v2 = ap[kbase + 2];
                    if (kbase + 3 < K) v3 = ap[kbase + 3];
                }
            }
            As[lk + 0][lr] = v0;
            As[lk + 1][lr] = v1;
            As[lk + 2][lr] = v2;
            As[lk + 3][lr] = v3;
        }
        {
            const int kk = k0 + bk;
            float v0 = 0.f, v1 = 0.f, v2 = 0.f, v3 = 0.f;
            if (kk < K) {
                const int nbase = n0 + bn;
                if (nbase + 3 < N) {
                    float4 v = *reinterpret_cast<const float4*>(W1 + (size_t)kk * N + nbase);
                    v0 = v.x; v1 = v.y; v2 = v.z; v3 = v.w;
                } else {
                    const float* wp = W1 + (size_t)kk * N;
                    if (nbase + 0 < N) v0 = wp[nbase + 0];
                    if (nbase + 1 < N) v1 = wp[nbase + 1];
                    if (nbase + 2 < N) v2 = wp[nbase + 2];
                    if (nbase + 3 < N) v3 = wp[nbase + 3];
                }
            }
            Bs[bk][bn + 0] = v0;
            Bs[bk][bn + 1] = v1;
            Bs[bk][bn + 2] = v2;
            Bs[bk][bn + 3] = v3;
        }
        __syncthreads();
        #pragma unroll
        for (int k = 0; k < BK; ++k) {
            float4 a = *reinterpret_cast<const float4*>(&As[k][ty * 4]);
            float4 b = *reinterpret_cast<const float4*>(&Bs[k][tx * 4]);
            float av[4] = {a.x, a.y, a.z, a.w};
            float bv[4] = {b.x, b.y, b.z, b.w};
            #pragma unroll
            for (int i = 0; i < 4; ++i)
                #pragma unroll
                for (int j = 0; j < 4; ++j)
                    acc[i][j] = fmaf(av[i], bv[j], acc[i][j]);
        }
        __syncthreads();
    }

    #pragma unroll
    for (int i = 0; i < 4; ++i) {
        const int row = m0 + ty * 4 + i;
        if (row >= M) continue;
        #pragma unroll
        for (int j = 0; j < 4; ++j) {
            const int col = n0 + tx * 4 + j;
            if (col >= N) continue;
            float v = acc[i][j];
            if (bias) v += bias[col];
            if (do_relu) v = fmaxf(v, 0.f);
            if (CBF) ((bf16_t*)Cv)[(size_t)row * ldc + col] = f2bf(v);
            else     ((float*)Cv)[(size_t)row * ldc + col] = v;
        }
    }
}

// ---------------- weight convert: W f32 [K,N] -> Wt bf16 [WT_LD][WT_LD] ----
// Wt[n][k] = W[k][n]; zero-padded (k>=K or n>=N).
__global__ void convert_wt(const float* __restrict__ W, bf16_t* __restrict__ Wt,
                           int K, int N) {
    int idx = blockIdx.x * blockDim.x + threadIdx.x;
    if (idx >= WT_LD * WT_LD) return;
    int n = idx / WT_LD, k = idx % WT_LD;
    float v = (k < K && n < N) ? W[(size_t)k * N + n] : 0.f;
    Wt[idx] = f2bf(v);
}

// ---------------- MFMA GEMM ----------------
// C[M,300](bf16, ldc=KPAD) = [relu]( A1@W1 (+ A2@W2) (+ bias) )
// A: bf16 [M, KPAD] row-major (K=300 used; pad cols arbitrary — Wt k-pad is 0).
// Wt: bf16 [WT_LD, WT_LD], Wt[n][k] = W[k][n].
// Tile 128x64, 4 waves (2m x 2n), each wave 64x32 = 4x2 fragments of 16x16x32.
#define MT_BM 128
#define MT_BN 64
#define MT_BK 32
#define ALD 40            // LDS row stride in bf16 (32 + 8 pad -> conflict-free frags)

template<bool DUAL>
__global__ __launch_bounds__(256) void gemm_mfma(
    const bf16_t* __restrict__ A1, const bf16_t* __restrict__ Wt1,
    const bf16_t* __restrict__ A2, const bf16_t* __restrict__ Wt2,
    const float* __restrict__ bias, bf16_t* __restrict__ C,
    int M, int do_relu)
{
    __shared__ __align__(16) bf16_t Alds[MT_BM][ALD];   // 10 KB
    __shared__ __align__(16) bf16_t Blds[MT_BN][ALD];   // 5 KB
    const int t = threadIdx.x;
    const int lane = t & 63;
    const int wave = t >> 6;
    const int wm = wave >> 1;          // 0..1 (m half)
    const int wn = wave & 1;           // 0..1 (n half)
    const int m0 = blockIdx.x * MT_BM;
    const int n0 = blockIdx.y * MT_BN;

    const int fr = lane & 15;          // fragment row/col
    const int kg = lane >> 4;          // k-group (8 elems)

    f32x4_t acc[4][2];
    #pragma unroll
    for (int i = 0; i < 4; ++i)
        #pragma unroll
        for (int j = 0; j < 2; ++j)
            acc[i][j] = f32x4_t{0.f, 0.f, 0.f, 0.f};

    const int NPH = DUAL ? 2 : 1;
    for (int ph = 0; ph < NPH; ++ph) {
        const bf16_t* __restrict__ A  = ph ? A2  : A1;
        const bf16_t* __restrict__ Wt = ph ? Wt2 : Wt1;

        for (int k0 = 0; k0 < KPAD; k0 += MT_BK) {
            // ---- stage A: 128 rows x 32 bf16 = 512 16B-chunks, 2 per thread ----
            #pragma unroll
            for (int cc = 0; cc < 2; ++cc) {
                const int c = t + cc * 256;
                const int row = c >> 2;            // 0..127
                const int cid = c & 3;             // 16B chunk in row
                uint4 v = *reinterpret_cast<const uint4*>(
                    A + (size_t)(m0 + row) * KPAD + k0 + cid * 8);
                *reinterpret_cast<uint4*>(&Alds[row][cid * 8]) = v;
            }
            // ---- stage B: 64 rows x 32 bf16 = 256 chunks, 1 per thread ----
            {
                const int row = t >> 2;            // 0..63
                const int cid = t & 3;
                uint4 v = *reinterpret_cast<const uint4*>(
                    Wt + (size_t)(n0 + row) * WT_LD + k0 + cid * 8);
                *reinterpret_cast<uint4*>(&Blds[row][cid * 8]) = v;
            }
            __syncthreads();

            bf16x8_t af[4], bfr[2];
            #pragma unroll
            for (int i = 0; i < 4; ++i)
                af[i] = *reinterpret_cast<const bf16x8_t*>(&Alds[wm * 64 + i * 16 + fr][kg * 8]);
            #pragma unroll
            for (int j = 0; j < 2; ++j)
                bfr[j] = *reinterpret_cast<const bf16x8_t*>(&Blds[wn * 32 + j * 16 + fr][kg * 8]);
            #pragma unroll
            for (int i = 0; i < 4; ++i)
                #pragma unroll
                for (int j = 0; j < 2; ++j)
                    acc[i][j] = __builtin_amdgcn_mfma_f32_16x16x32_bf16(
                        af[i], bfr[j], acc[i][j], 0, 0, 0);
            __syncthreads();
        }
    }

    // ---- epilogue: D col=lane&15, row=(lane>>4)*4+q ----
    #pragma unroll
    for (int j = 0; j < 2; ++j) {
        const int col = n0 + wn * 32 + j * 16 + fr;
        if (col >= HIDDEN) continue;
        const float bb = bias ? bias[col] : 0.f;
        #pragma unroll
        for (int i = 0; i < 4; ++i) {
            const int rbase = m0 + wm * 64 + i * 16 + kg * 4;
            #pragma unroll
            for (int q = 0; q < 4; ++q) {
                const int row = rbase + q;
                if (row >= M) continue;
                float v = acc[i][j][q] + bb;
                if (do_relu) v = fmaxf(v, 0.f);
                C[(size_t)row * KPAD + col] = f2bf(v);
            }
        }
    }
}

// ---------------- CSR build over dst ----------------
__global__ void csr_hist(const int* __restrict__ dst, int* __restrict__ cnt, int n) {
    int i = blockIdx.x * blockDim.x + threadIdx.x;
    if (i < n) atomicAdd(&cnt[dst[i]], 1);
}

#define SCAN_T 1024
__global__ __launch_bounds__(SCAN_T) void csr_scan(
    const int* __restrict__ cnt, int* __restrict__ row_ptr) {
    __shared__ int sums[SCAN_T];
    const int t = threadIdx.x;
    const int per = (N_ATOMS + SCAN_T - 1) / SCAN_T;
    const int base = t * per;
    int local = 0;
    for (int i = 0; i < per; ++i) {
        int idx = base + i;
        if (idx < N_ATOMS) local += cnt[idx];
    }
    sums[t] = local;
    __syncthreads();
    for (int off = 1; off < SCAN_T; off <<= 1) {
        int v = (t >= off) ? sums[t - off] : 0;
        __syncthreads();
        if (t >= off) sums[t] += v;
        __syncthreads();
    }
    int prefix = (t == 0) ? 0 : sums[t - 1];
    for (int i = 0; i < per; ++i) {
        int idx = base + i;
        if (idx < N_ATOMS) {
            row_ptr[idx] = prefix;
            prefix += cnt[idx];
        }
    }
    if (t == SCAN_T - 1) row_ptr[N_ATOMS] = prefix;
}

__global__ void csr_fill(const int* __restrict__ dst, int* __restrict__ pos,
                         int* __restrict__ eid, int n) {
    int i = blockIdx.x * blockDim.x + threadIdx.x;
    if (i < n) {
        int p = atomicAdd(&pos[dst[i]], 1);
        eid[p] = i;
    }
}

// ---- agg[v] = sum_{e: dst=v} relu(hW[src_e] + ea_e @ WiB), bf16 out ----
__global__ __launch_bounds__(256) void gather_agg(
    const bf16_t* __restrict__ hW, const float* __restrict__ edge_attr,
    const int* __restrict__ src, const int* __restrict__ row_ptr,
    const int* __restrict__ eid, const float* __restrict__ WiB,
    bf16_t* __restrict__ agg)
{
    __shared__ __align__(16) float sWiB[BOND_FDIM * HIDDEN];   // 16.8 KB
    const int t = threadIdx.x;
    for (int i = t; i < BOND_FDIM * HIDDEN; i += 256) sWiB[i] = WiB[i];
    __syncthreads();

    const int wave = t >> 6;
    const int lane = t & 63;
    const int v = blockIdx.x * 4 + wave;
    if (v >= N_ATOMS) return;
    const int beg = row_ptr[v];
    const int end = row_ptr[v + 1];

    float acc[5] = {0.f, 0.f, 0.f, 0.f, 0.f};
    for (int idx = beg; idx < end; ++idx) {
        const int e = eid[idx];
        const int s = src[e];
        float eav[BOND_FDIM];
        #pragma unroll
        for (int k = 0; k < BOND_FDIM; ++k)
            eav[k] = edge_attr[(size_t)e * BOND_FDIM + k];
        const bf16_t* __restrict__ hrow = hW + (size_t)s * KPAD;
        #pragma unroll
        for (int c = 0; c < 5; ++c) {
            const int j = lane + 64 * c;
            if (j < HIDDEN) {
                float m = bf2f(hrow[j]);
                #pragma unroll
                for (int k = 0; k < BOND_FDIM; ++k)
                    m = fmaf(eav[k], sWiB[k * HIDDEN + j], m);
                acc[c] += fmaxf(m, 0.f);
            }
        }
    }
    bf16_t* __restrict__ arow = agg + (size_t)v * KPAD;
    #pragma unroll
    for (int c = 0; c < 5; ++c) {
        const int j = lane + 64 * c;
        if (j < HIDDEN) arow[j] = f2bf(acc[c]);
    }
}

// Segment-sum of bf16 h_v (stride KPAD) into fp32 mol_repr (batch sorted).
#define ATOMS_PER_BLOCK 32
__global__ __launch_bounds__(320) void mol_reduce(
    const bf16_t* __restrict__ hv, const int* __restrict__ batch,
    float* __restrict__ mol, int n_atoms)
{
    const int j = threadIdx.x;
    if (j >= HIDDEN) return;
    const int a0 = blockIdx.x * ATOMS_PER_BLOCK;
    const int aend = min(a0 + ATOMS_PER_BLOCK, n_atoms);
    float acc = 0.f;
    int cur = batch[a0];
    for (int a = a0; a < aend; ++a) {
        const int b = batch[a];
        if (b != cur) {
            atomicAdd(&mol[(size_t)cur * HIDDEN + j], acc);
            acc = 0.f;
            cur = b;
        }
        acc += bf2f(hv[(size_t)a * KPAD + j]);
    }
    atomicAdd(&mol[(size_t)cur * HIDDEN + j], acc);
}

__global__ void fill_const(float* p, int n, float v) {
    int i = blockIdx.x * blockDim.x + threadIdx.x;
    if (i < n) p[i] = v;
}

static inline size_t align256(size_t x) { return (x + 255) & ~(size_t)255; }

extern "C" void kernel_launch(void* const* d_in, const int* in_sizes, int n_in,
                              void* d_out, int out_size, void* d_ws, size_t ws_size,
                              hipStream_t stream) {
    const float* x       = (const float*)d_in[0];
    const int*   ei      = (const int*)  d_in[1];
    const float* ea      = (const float*)d_in[2];
    const int*   batch   = (const int*)  d_in[3];
    const float* atom_W  = (const float*)d_in[4];
    const float* atom_b  = (const float*)d_in[5];
    // d_in[6] bond_W, d_in[7] bond_b, d_in[9] Wh: dead code
    const float* Wi      = (const float*)d_in[8];    // [314,300]
    const float* Wo      = (const float*)d_in[10];   // [600,300]
    const float* Wo_b    = (const float*)d_in[11];
    const float* f1W     = (const float*)d_in[12];
    const float* f1b     = (const float*)d_in[13];
    const float* f2W     = (const float*)d_in[14];
    const float* f2b     = (const float*)d_in[15];

    const int* src = ei;            // edge_index[0]
    const int* dst = ei + N_EDGES;  // edge_index[1]

    const float* Wi_top = Wi;                            // [300,300]
    const float* WiB    = Wi + (size_t)HIDDEN * HIDDEN;  // [14,300]
    const float* Wo_top = Wo;                            // [300,300]
    const float* Wo_bot = Wo + (size_t)HIDDEN * HIDDEN;  // [300,300]

    // ---- workspace ----
    const size_t hv_b   = (size_t)N_ATOMS * KPAD * sizeof(bf16_t);  // 64 MB
    const size_t wt_b   = (size_t)WT_LD * WT_LD * sizeof(bf16_t);   // 200 KB
    const size_t mol_f  = (size_t)N_MOLS * HIDDEN * sizeof(float);  // 4.9 MB
    const size_t rp_b   = (size_t)(N_ATOMS + 1) * sizeof(int);
    const size_t cnt_b  = (size_t)N_ATOMS * sizeof(int);
    const size_t eid_b  = (size_t)N_EDGES * sizeof(int);
    const size_t needed = 3 * align256(hv_b) + 3 * align256(wt_b)
                        + 2 * align256(mol_f)
                        + align256(rp_b) + align256(cnt_b) + align256(eid_b)
                        + 65536;   // slack for benign OOB-row staging reads
    if (ws_size < needed) {
        fill_const<<<dim3((out_size + 255) / 256), dim3(256), 0, stream>>>(
            (float*)d_out, out_size, 1.0e6f);   // canary: ws too small
        return;
    }
    char* p = (char*)d_ws;
    bf16_t* bufA   = (bf16_t*)p; p += align256(hv_b);    // hv ping
    bf16_t* bufB   = (bf16_t*)p; p += align256(hv_b);    // hW / hv_out (aliased)
    bf16_t* agg    = (bf16_t*)p; p += align256(hv_b);
    bf16_t* Wt_i   = (bf16_t*)p; p += align256(wt_b);    // Wi_top^T
    bf16_t* Wt_o1  = (bf16_t*)p; p += align256(wt_b);    // Wo_top^T
    bf16_t* Wt_o2  = (bf16_t*)p; p += align256(wt_b);    // Wo_bot^T
    float*  mol    = (float*)p;  p += align256(mol_f);
    float*  ffnh   = (float*)p;  p += align256(mol_f);
    int*    row_ptr= (int*)p;    p += align256(rp_b);
    int*    cntpos = (int*)p;    p += align256(cnt_b);
    int*    eid    = (int*)p;    p += align256(eid_b);

    dim3 blk(256);
    dim3 gA((N_ATOMS + BM - 1) / BM, (HIDDEN + BN - 1) / BN);   // scalar atom embed
    dim3 gM((N_MOLS + BM - 1) / BM, (HIDDEN + BN - 1) / BN);
    dim3 gO((N_MOLS + BM - 1) / BM, (N_LABELS + BN - 1) / BN);
    dim3 gE((N_EDGES + 255) / 256);
    dim3 gW((WT_LD * WT_LD + 255) / 256);
    dim3 gMF((N_ATOMS + MT_BM - 1) / MT_BM, KPAD / MT_BN);      // 782 x 5

    // ---- one-time per call: weight transposes + CSR ----
    convert_wt<<<gW, blk, 0, stream>>>(Wi_top, Wt_i,  HIDDEN, HIDDEN);
    convert_wt<<<gW, blk, 0, stream>>>(Wo_top, Wt_o1, HIDDEN, HIDDEN);
    convert_wt<<<gW, blk, 0, stream>>>(Wo_bot, Wt_o2, HIDDEN, HIDDEN);

    hipMemsetAsync(cntpos, 0, cnt_b, stream);
    csr_hist<<<gE, blk, 0, stream>>>(dst, cntpos, N_EDGES);
    csr_scan<<<dim3(1), dim3(SCAN_T), 0, stream>>>(cntpos, row_ptr);
    hipMemcpyAsync(cntpos, row_ptr, cnt_b, hipMemcpyDeviceToDevice, stream);
    csr_fill<<<gE, blk, 0, stream>>>(dst, cntpos, eid, N_EDGES);

    // 1) h_v = relu(x @ atom_W + atom_b)   [scalar f32 GEMM, bf16 out, ldc=KPAD]
    gemm_fused<true><<<gA, blk, 0, stream>>>(
        x, atom_W, ATOM_FDIM, atom_b, bufA, N_ATOMS, HIDDEN, KPAD, 1);

    bf16_t* hv_in   = bufA;
    bf16_t* scratch = bufB;   // holds hW, then hv_out
    for (int it = 0; it < DEPTH; ++it) {
        // 2a) hW = h_v @ Wi_top              [MFMA, no relu, no bias]
        gemm_mfma<false><<<gMF, blk, 0, stream>>>(
            hv_in, Wt_i, nullptr, nullptr, nullptr, scratch, N_ATOMS, 0);
        // 2b) agg = CSR-gather of relu(hW[src] + ea@WiB)
        gather_agg<<<dim3((N_ATOMS + 3) / 4), blk, 0, stream>>>(
            scratch, ea, src, row_ptr, eid, WiB, agg);
        // 2c) h_v' = relu(h_v @ Wo_top + agg @ Wo_bot + Wo_b)   [MFMA dual]
        gemm_mfma<true><<<gMF, blk, 0, stream>>>(
            hv_in, Wt_o1, agg, Wt_o2, Wo_b, scratch, N_ATOMS, 1);
        bf16_t* tmp = hv_in; hv_in = scratch; scratch = tmp;
    }

    // 3) mol_repr = segment_sum(h_v, batch)
    hipMemsetAsync(mol, 0, mol_f, stream);
    mol_reduce<<<dim3((N_ATOMS + ATOMS_PER_BLOCK - 1) / ATOMS_PER_BLOCK), dim3(320), 0, stream>>>(
        hv_in, batch, mol, N_ATOMS);

    // 4) ffn [scalar f32]
    gemm_fused<false><<<gM, blk, 0, stream>>>(
        mol, f1W, HIDDEN, f1b, ffnh, N_MOLS, HIDDEN, HIDDEN, 1);
    gemm_fused<false><<<gO, blk, 0, stream>>>(
        ffnh, f2W, HIDDEN, f2b, (float*)d_out, N_MOLS, N_LABELS, N_LABELS, 0);
}

// Round 8
// 1825.325 us; speedup vs baseline: 2.9094x; 1.0352x over previous
//
#include <hip/hip_runtime.h>

#define N_ATOMS 100000
#define N_EDGES 400000
#define N_MOLS  4096
#define ATOM_FDIM 133
#define BOND_FDIM 14
#define HIDDEN 300
#define DEPTH 3
#define N_LABELS 12

#define KPAD 320          // row stride for bf16 activation buffers (and Wt k-stride)
#define XKP  160          // padded K for atom-embed input x (133 -> 160)

#define BM 64
#define BN 64
#define BK 16

typedef unsigned short bf16_t;
typedef __bf16 bf16x8_t __attribute__((ext_vector_type(8)));
typedef float f32x4_t __attribute__((ext_vector_type(4)));

__device__ __forceinline__ float bf2f(bf16_t h) {
    return __uint_as_float(((unsigned int)h) << 16);
}
__device__ __forceinline__ bf16_t f2bf(float f) {
    unsigned int u = __float_as_uint(f);
    u = u + 0x7FFFu + ((u >> 16) & 1u);   // round-to-nearest-even
    return (bf16_t)(u >> 16);
}

// ---------------- scalar GEMM (ffn only: tiny M) ----------------
template<bool CBF>
__global__ __launch_bounds__(256) void gemm_fused(
    const float* __restrict__ A1, const float* __restrict__ W1, int K1,
    const float* __restrict__ bias, void* __restrict__ Cv,
    int M, int N, int ldc, int do_relu)
{
    __shared__ __align__(16) float As[BK][BM + 4];
    __shared__ __align__(16) float Bs[BK][BN];
    const int t  = threadIdx.x;
    const int tx = t & 15;
    const int ty = t >> 4;
    const int m0 = blockIdx.x * BM;
    const int n0 = blockIdx.y * BN;

    const int lr = t >> 2;
    const int lk = (t & 3) * 4;
    const int bk = t >> 4;
    const int bn = (t & 15) * 4;

    float acc[4][4] = {};
    const int K = K1;
    const bool k4 = ((K & 3) == 0);

    for (int k0 = 0; k0 < K; k0 += BK) {
        {
            const int row = m0 + lr;
            const int kbase = k0 + lk;
            float v0 = 0.f, v1 = 0.f, v2 = 0.f, v3 = 0.f;
            if (row < M) {
                const float* ap = A1 + (size_t)row * K;
                if (k4 && (kbase + 3 < K)) {
                    float4 v = *reinterpret_cast<const float4*>(ap + kbase);
                    v0 = v.x; v1 = v.y; v2 = v.z; v3 = v.w;
                } else {
                    if (kbase + 0 < K) v0 = ap[kbase + 0];
                    if (kbase + 1 < K) v1 = ap[kbase + 1];
                    if (kbase + 2 < K) v2 = ap[kbase + 2];
                    if (kbase + 3 < K) v3 = ap[kbase + 3];
                }
            }
            As[lk + 0][lr] = v0;
            As[lk + 1][lr] = v1;
            As[lk + 2][lr] = v2;
            As[lk + 3][lr] = v3;
        }
        {
            const int kk = k0 + bk;
            float v0 = 0.f, v1 = 0.f, v2 = 0.f, v3 = 0.f;
            if (kk < K) {
                const int nbase = n0 + bn;
                if (nbase + 3 < N) {
                    float4 v = *reinterpret_cast<const float4*>(W1 + (size_t)kk * N + nbase);
                    v0 = v.x; v1 = v.y; v2 = v.z; v3 = v.w;
                } else {
                    const float* wp = W1 + (size_t)kk * N;
                    if (nbase + 0 < N) v0 = wp[nbase + 0];
                    if (nbase + 1 < N) v1 = wp[nbase + 1];
                    if (nbase + 2 < N) v2 = wp[nbase + 2];
                    if (nbase + 3 < N) v3 = wp[nbase + 3];
                }
            }
            Bs[bk][bn + 0] = v0;
            Bs[bk][bn + 1] = v1;
            Bs[bk][bn + 2] = v2;
            Bs[bk][bn + 3] = v3;
        }
        __syncthreads();
        #pragma unroll
        for (int k = 0; k < BK; ++k) {
            float4 a = *reinterpret_cast<const float4*>(&As[k][ty * 4]);
            float4 b = *reinterpret_cast<const float4*>(&Bs[k][tx * 4]);
            float av[4] = {a.x, a.y, a.z, a.w};
            float bv[4] = {b.x, b.y, b.z, b.w};
            #pragma unroll
            for (int i = 0; i < 4; ++i)
                #pragma unroll
                for (int j = 0; j < 4; ++j)
                    acc[i][j] = fmaf(av[i], bv[j], acc[i][j]);
        }
        __syncthreads();
    }

    #pragma unroll
    for (int i = 0; i < 4; ++i) {
        const int row = m0 + ty * 4 + i;
        if (row >= M) continue;
        #pragma unroll
        for (int j = 0; j < 4; ++j) {
            const int col = n0 + tx * 4 + j;
            if (col >= N) continue;
            float v = acc[i][j];
            if (bias) v += bias[col];
            if (do_relu) v = fmaxf(v, 0.f);
            if (CBF) ((bf16_t*)Cv)[(size_t)row * ldc + col] = f2bf(v);
            else     ((float*)Cv)[(size_t)row * ldc + col] = v;
        }
    }
}

// ---- weight convert: W f32 [K,N] -> Wt bf16 [320 rows n][LDA cols k], zero-pad ----
__global__ void convert_wt(const float* __restrict__ W, bf16_t* __restrict__ Wt,
                           int K, int N, int lda) {
    int idx = blockIdx.x * blockDim.x + threadIdx.x;
    if (idx >= 320 * lda) return;
    int n = idx / lda, k = idx % lda;
    float v = (k < K && n < N) ? W[(size_t)k * N + n] : 0.f;
    Wt[idx] = f2bf(v);
}

// ---- x f32 [N_ATOMS,133] -> bf16 [N_ATOMS, XKP], zero-pad ----
__global__ void convert_x(const float* __restrict__ x, bf16_t* __restrict__ xb) {
    int i = blockIdx.x * blockDim.x + threadIdx.x;
    if (i >= N_ATOMS * XKP) return;
    int r = i / XKP, k = i % XKP;
    xb[i] = f2bf(k < ATOM_FDIM ? x[(size_t)r * ATOM_FDIM + k] : 0.f);
}

// ---------------- MFMA GEMM ----------------
// C[M,300](bf16, ldc=KPAD) = [relu]( A1@W1 (+ A2@W2) (+ bias) )
// A: bf16 [M, LDA] row-major; Wt: bf16 [320][LDA], Wt[n][k] = W[k][n], k-pad 0.
// Tile 128x64, 4 waves (2m x 2n), each wave 64x32 = 4x2 frags of 16x16x32.
#define MT_BM 128
#define MT_BN 64
#define MT_BK 32
#define ALD 40            // LDS row stride (32 + 8 pad)

template<bool DUAL, int KMAX, int LDA>
__global__ __launch_bounds__(256) void gemm_mfma(
    const bf16_t* __restrict__ A1, const bf16_t* __restrict__ Wt1,
    const bf16_t* __restrict__ A2, const bf16_t* __restrict__ Wt2,
    const float* __restrict__ bias, bf16_t* __restrict__ C,
    int M, int do_relu)
{
    __shared__ __align__(16) bf16_t Alds[MT_BM][ALD];   // 10 KB
    __shared__ __align__(16) bf16_t Blds[MT_BN][ALD];   // 5 KB
    const int t = threadIdx.x;
    const int lane = t & 63;
    const int wave = t >> 6;
    const int wm = wave >> 1;
    const int wn = wave & 1;
    const int m0 = blockIdx.x * MT_BM;
    const int n0 = blockIdx.y * MT_BN;

    const int fr = lane & 15;
    const int kg = lane >> 4;

    f32x4_t acc[4][2];
    #pragma unroll
    for (int i = 0; i < 4; ++i)
        #pragma unroll
        for (int j = 0; j < 2; ++j)
            acc[i][j] = f32x4_t{0.f, 0.f, 0.f, 0.f};

    const int NPH = DUAL ? 2 : 1;
    for (int ph = 0; ph < NPH; ++ph) {
        const bf16_t* __restrict__ A  = ph ? A2  : A1;
        const bf16_t* __restrict__ Wt = ph ? Wt2 : Wt1;

        for (int k0 = 0; k0 < KMAX; k0 += MT_BK) {
            #pragma unroll
            for (int cc = 0; cc < 2; ++cc) {
                const int c = t + cc * 256;
                const int row = c >> 2;
                const int cid = c & 3;
                uint4 v = *reinterpret_cast<const uint4*>(
                    A + (size_t)(m0 + row) * LDA + k0 + cid * 8);
                *reinterpret_cast<uint4*>(&Alds[row][cid * 8]) = v;
            }
            {
                const int row = t >> 2;
                const int cid = t & 3;
                uint4 v = *reinterpret_cast<const uint4*>(
                    Wt + (size_t)(n0 + row) * LDA + k0 + cid * 8);
                *reinterpret_cast<uint4*>(&Blds[row][cid * 8]) = v;
            }
            __syncthreads();

            bf16x8_t af[4], bfr[2];
            #pragma unroll
            for (int i = 0; i < 4; ++i)
                af[i] = *reinterpret_cast<const bf16x8_t*>(&Alds[wm * 64 + i * 16 + fr][kg * 8]);
            #pragma unroll
            for (int j = 0; j < 2; ++j)
                bfr[j] = *reinterpret_cast<const bf16x8_t*>(&Blds[wn * 32 + j * 16 + fr][kg * 8]);
            #pragma unroll
            for (int i = 0; i < 4; ++i)
                #pragma unroll
                for (int j = 0; j < 2; ++j)
                    acc[i][j] = __builtin_amdgcn_mfma_f32_16x16x32_bf16(
                        af[i], bfr[j], acc[i][j], 0, 0, 0);
            __syncthreads();
        }
    }

    #pragma unroll
    for (int j = 0; j < 2; ++j) {
        const int col = n0 + wn * 32 + j * 16 + fr;
        if (col >= HIDDEN) continue;
        const float bb = bias ? bias[col] : 0.f;
        #pragma unroll
        for (int i = 0; i < 4; ++i) {
            const int rbase = m0 + wm * 64 + i * 16 + kg * 4;
            #pragma unroll
            for (int q = 0; q < 4; ++q) {
                const int row = rbase + q;
                if (row >= M) continue;
                float v = acc[i][j][q] + bb;
                if (do_relu) v = fmaxf(v, 0.f);
                C[(size_t)row * KPAD + col] = f2bf(v);
            }
        }
    }
}

// ---------------- CSR build over dst ----------------
__global__ void csr_hist(const int* __restrict__ dst, int* __restrict__ cnt, int n) {
    int i = blockIdx.x * blockDim.x + threadIdx.x;
    if (i < n) atomicAdd(&cnt[dst[i]], 1);
}

#define SCAN_T 1024
__global__ __launch_bounds__(SCAN_T) void csr_scan(
    const int* __restrict__ cnt, int* __restrict__ row_ptr) {
    __shared__ int sums[SCAN_T];
    const int t = threadIdx.x;
    const int per = (N_ATOMS + SCAN_T - 1) / SCAN_T;
    const int base = t * per;
    int local = 0;
    for (int i = 0; i < per; ++i) {
        int idx = base + i;
        if (idx < N_ATOMS) local += cnt[idx];
    }
    sums[t] = local;
    __syncthreads();
    for (int off = 1; off < SCAN_T; off <<= 1) {
        int v = (t >= off) ? sums[t - off] : 0;
        __syncthreads();
        if (t >= off) sums[t] += v;
        __syncthreads();
    }
    int prefix = (t == 0) ? 0 : sums[t - 1];
    for (int i = 0; i < per; ++i) {
        int idx = base + i;
        if (idx < N_ATOMS) {
            row_ptr[idx] = prefix;
            prefix += cnt[idx];
        }
    }
    if (t == SCAN_T - 1) row_ptr[N_ATOMS] = prefix;
}

__global__ void csr_fill(const int* __restrict__ dst, int* __restrict__ pos,
                         int* __restrict__ eid, int n) {
    int i = blockIdx.x * blockDim.x + threadIdx.x;
    if (i < n) {
        int p = atomicAdd(&pos[dst[i]], 1);
        eid[p] = i;
    }
}

// ---- agg[v] = sum_{e: dst=v} relu(hW[src_e] + ea_e @ WiB), bf16 out ----
// v2: 16 atoms/block (4/wave, consecutive), 2-deep edge pipeline, float2 ea loads.
__global__ __launch_bounds__(256) void gather_agg(
    const bf16_t* __restrict__ hW, const float* __restrict__ edge_attr,
    const int* __restrict__ src, const int* __restrict__ row_ptr,
    const int* __restrict__ eid, const float* __restrict__ WiB,
    bf16_t* __restrict__ agg)
{
    __shared__ __align__(16) float sWiB[BOND_FDIM * HIDDEN];   // 16.8 KB
    const int t = threadIdx.x;
    for (int i = t; i < BOND_FDIM * HIDDEN; i += 256) sWiB[i] = WiB[i];
    __syncthreads();

    const int wave = t >> 6;
    const int lane = t & 63;
    const int vbase = blockIdx.x * 16 + wave * 4;

    #pragma unroll 1
    for (int a = 0; a < 4; ++a) {
        const int v = vbase + a;
        if (v >= N_ATOMS) return;
        const int beg = row_ptr[v];
        const int end = row_ptr[v + 1];

        float acc0 = 0.f, acc1 = 0.f, acc2 = 0.f, acc3 = 0.f, acc4 = 0.f;

        int e_cur = 0, s_cur = 0;
        if (beg < end) { e_cur = eid[beg]; s_cur = src[e_cur]; }
        #pragma unroll 1
        for (int idx = beg; idx < end; ++idx) {
            const int e = e_cur, s = s_cur;
            if (idx + 1 < end) {             // prefetch next edge's indices
                e_cur = eid[idx + 1];
                s_cur = src[e_cur];
            }
            const bf16_t* __restrict__ hrow = hW + (size_t)s * KPAD;
            // issue row loads (independent, in flight together)
            const bf16_t h0 = hrow[lane];
            const bf16_t h1 = hrow[lane + 64];
            const bf16_t h2 = hrow[lane + 128];
            const bf16_t h3 = hrow[lane + 192];
            const bf16_t h4 = (lane < HIDDEN - 256) ? hrow[lane + 256] : (bf16_t)0;
            const float* __restrict__ ep = edge_attr + (size_t)e * BOND_FDIM;
            float eav[BOND_FDIM];
            #pragma unroll
            for (int q = 0; q < BOND_FDIM / 2; ++q) {   // 7 x float2 (8B-aligned)
                float2 w = *reinterpret_cast<const float2*>(ep + 2 * q);
                eav[2 * q] = w.x; eav[2 * q + 1] = w.y;
            }
            float m0 = bf2f(h0), m1 = bf2f(h1), m2 = bf2f(h2), m3 = bf2f(h3), m4 = bf2f(h4);
            #pragma unroll
            for (int k = 0; k < BOND_FDIM; ++k) {
                const float* wk = &sWiB[k * HIDDEN];
                const float ek = eav[k];
                m0 = fmaf(ek, wk[lane], m0);
                m1 = fmaf(ek, wk[lane + 64], m1);
                m2 = fmaf(ek, wk[lane + 128], m2);
                m3 = fmaf(ek, wk[lane + 192], m3);
                if (lane < HIDDEN - 256) m4 = fmaf(ek, wk[lane + 256], m4);
            }
            acc0 += fmaxf(m0, 0.f);
            acc1 += fmaxf(m1, 0.f);
            acc2 += fmaxf(m2, 0.f);
            acc3 += fmaxf(m3, 0.f);
            acc4 += fmaxf(m4, 0.f);
        }
        bf16_t* __restrict__ arow = agg + (size_t)v * KPAD;
        arow[lane]       = f2bf(acc0);
        arow[lane + 64]  = f2bf(acc1);
        arow[lane + 128] = f2bf(acc2);
        arow[lane + 192] = f2bf(acc3);
        if (lane < HIDDEN - 256) arow[lane + 256] = f2bf(acc4);
    }
}

// Segment-sum of bf16 h_v (stride KPAD) into fp32 mol_repr (batch sorted).
#define ATOMS_PER_BLOCK 32
__global__ __launch_bounds__(320) void mol_reduce(
    const bf16_t* __restrict__ hv, const int* __restrict__ batch,
    float* __restrict__ mol, int n_atoms)
{
    const int j = threadIdx.x;
    if (j >= HIDDEN) return;
    const int a0 = blockIdx.x * ATOMS_PER_BLOCK;
    const int aend = min(a0 + ATOMS_PER_BLOCK, n_atoms);
    float acc = 0.f;
    int cur = batch[a0];
    for (int a = a0; a < aend; ++a) {
        const int b = batch[a];
        if (b != cur) {
            atomicAdd(&mol[(size_t)cur * HIDDEN + j], acc);
            acc = 0.f;
            cur = b;
        }
        acc += bf2f(hv[(size_t)a * KPAD + j]);
    }
    atomicAdd(&mol[(size_t)cur * HIDDEN + j], acc);
}

__global__ void fill_const(float* p, int n, float v) {
    int i = blockIdx.x * blockDim.x + threadIdx.x;
    if (i < n) p[i] = v;
}

static inline size_t align256(size_t x) { return (x + 255) & ~(size_t)255; }

extern "C" void kernel_launch(void* const* d_in, const int* in_sizes, int n_in,
                              void* d_out, int out_size, void* d_ws, size_t ws_size,
                              hipStream_t stream) {
    const float* x       = (const float*)d_in[0];
    const int*   ei      = (const int*)  d_in[1];
    const float* ea      = (const float*)d_in[2];
    const int*   batch   = (const int*)  d_in[3];
    const float* atom_W  = (const float*)d_in[4];
    const float* atom_b  = (const float*)d_in[5];
    // d_in[6] bond_W, d_in[7] bond_b, d_in[9] Wh: dead code
    const float* Wi      = (const float*)d_in[8];    // [314,300]
    const float* Wo      = (const float*)d_in[10];   // [600,300]
    const float* Wo_b    = (const float*)d_in[11];
    const float* f1W     = (const float*)d_in[12];
    const float* f1b     = (const float*)d_in[13];
    const float* f2W     = (const float*)d_in[14];
    const float* f2b     = (const float*)d_in[15];

    const int* src = ei;            // edge_index[0]
    const int* dst = ei + N_EDGES;  // edge_index[1]

    const float* Wi_top = Wi;                            // [300,300]
    const float* WiB    = Wi + (size_t)HIDDEN * HIDDEN;  // [14,300]
    const float* Wo_top = Wo;                            // [300,300]
    const float* Wo_bot = Wo + (size_t)HIDDEN * HIDDEN;  // [300,300]

    // ---- workspace ----
    const size_t hv_b   = (size_t)N_ATOMS * KPAD * sizeof(bf16_t);  // 64 MB
    const size_t xb_b   = (size_t)N_ATOMS * XKP  * sizeof(bf16_t);  // 32 MB
    const size_t wt_b   = (size_t)320 * KPAD * sizeof(bf16_t);      // 200 KB
    const size_t wta_b  = (size_t)320 * XKP  * sizeof(bf16_t);      // 100 KB
    const size_t mol_f  = (size_t)N_MOLS * HIDDEN * sizeof(float);  // 4.9 MB
    const size_t rp_b   = (size_t)(N_ATOMS + 1) * sizeof(int);
    const size_t cnt_b  = (size_t)N_ATOMS * sizeof(int);
    const size_t eid_b  = (size_t)N_EDGES * sizeof(int);
    const size_t needed = 3 * align256(hv_b) + align256(xb_b)
                        + 3 * align256(wt_b) + align256(wta_b)
                        + 2 * align256(mol_f)
                        + align256(rp_b) + align256(cnt_b) + align256(eid_b)
                        + 65536;   // slack for benign OOB-row staging reads
    if (ws_size < needed) {
        fill_const<<<dim3((out_size + 255) / 256), dim3(256), 0, stream>>>(
            (float*)d_out, out_size, 1.0e6f);   // canary: ws too small
        return;
    }
    char* p = (char*)d_ws;
    bf16_t* bufA   = (bf16_t*)p; p += align256(hv_b);    // hv ping
    bf16_t* bufB   = (bf16_t*)p; p += align256(hv_b);    // hW / hv_out (aliased)
    bf16_t* agg    = (bf16_t*)p; p += align256(hv_b);
    bf16_t* xb     = (bf16_t*)p; p += align256(xb_b);    // x in bf16, [N_ATOMS, XKP]
    bf16_t* Wt_i   = (bf16_t*)p; p += align256(wt_b);    // Wi_top^T
    bf16_t* Wt_o1  = (bf16_t*)p; p += align256(wt_b);    // Wo_top^T
    bf16_t* Wt_o2  = (bf16_t*)p; p += align256(wt_b);    // Wo_bot^T
    bf16_t* Wt_a   = (bf16_t*)p; p += align256(wta_b);   // atom_W^T [320][XKP]
    float*  mol    = (float*)p;  p += align256(mol_f);
    float*  ffnh   = (float*)p;  p += align256(mol_f);
    int*    row_ptr= (int*)p;    p += align256(rp_b);
    int*    cntpos = (int*)p;    p += align256(cnt_b);
    int*    eid    = (int*)p;    p += align256(eid_b);

    dim3 blk(256);
    dim3 gM((N_MOLS + BM - 1) / BM, (HIDDEN + BN - 1) / BN);
    dim3 gO((N_MOLS + BM - 1) / BM, (N_LABELS + BN - 1) / BN);
    dim3 gE((N_EDGES + 255) / 256);
    dim3 gW((320 * KPAD + 255) / 256);
    dim3 gWa((320 * XKP + 255) / 256);
    dim3 gX((N_ATOMS * XKP + 255) / 256);
    dim3 gMF((N_ATOMS + MT_BM - 1) / MT_BM, KPAD / MT_BN);      // 782 x 5
    dim3 gGA((N_ATOMS + 15) / 16);                              // 6250

    // ---- one-time per call: converts + CSR ----
    convert_wt<<<gW,  blk, 0, stream>>>(Wi_top, Wt_i,  HIDDEN, HIDDEN, KPAD);
    convert_wt<<<gW,  blk, 0, stream>>>(Wo_top, Wt_o1, HIDDEN, HIDDEN, KPAD);
    convert_wt<<<gW,  blk, 0, stream>>>(Wo_bot, Wt_o2, HIDDEN, HIDDEN, KPAD);
    convert_wt<<<gWa, blk, 0, stream>>>(atom_W, Wt_a,  ATOM_FDIM, HIDDEN, XKP);
    convert_x<<<gX,   blk, 0, stream>>>(x, xb);

    hipMemsetAsync(cntpos, 0, cnt_b, stream);
    csr_hist<<<gE, blk, 0, stream>>>(dst, cntpos, N_EDGES);
    csr_scan<<<dim3(1), dim3(SCAN_T), 0, stream>>>(cntpos, row_ptr);
    hipMemcpyAsync(cntpos, row_ptr, cnt_b, hipMemcpyDeviceToDevice, stream);
    csr_fill<<<gE, blk, 0, stream>>>(dst, cntpos, eid, N_EDGES);

    // 1) h_v = relu(x @ atom_W + atom_b)   [MFMA, K=160]
    gemm_mfma<false, XKP, XKP><<<gMF, blk, 0, stream>>>(
        xb, Wt_a, nullptr, nullptr, atom_b, bufA, N_ATOMS, 1);

    bf16_t* hv_in   = bufA;
    bf16_t* scratch = bufB;   // holds hW, then hv_out
    for (int it = 0; it < DEPTH; ++it) {
        // 2a) hW = h_v @ Wi_top              [MFMA]
        gemm_mfma<false, KPAD, KPAD><<<gMF, blk, 0, stream>>>(
            hv_in, Wt_i, nullptr, nullptr, nullptr, scratch, N_ATOMS, 0);
        // 2b) agg = CSR-gather of relu(hW[src] + ea@WiB)
        gather_agg<<<gGA, blk, 0, stream>>>(
            scratch, ea, src, row_ptr, eid, WiB, agg);
        // 2c) h_v' = relu(h_v @ Wo_top + agg @ Wo_bot + Wo_b)   [MFMA dual]
        gemm_mfma<true, KPAD, KPAD><<<gMF, blk, 0, stream>>>(
            hv_in, Wt_o1, agg, Wt_o2, Wo_b, scratch, N_ATOMS, 1);
        bf16_t* tmp = hv_in; hv_in = scratch; scratch = tmp;
    }

    // 3) mol_repr = segment_sum(h_v, batch)
    hipMemsetAsync(mol, 0, mol_f, stream);
    mol_reduce<<<dim3((N_ATOMS + ATOMS_PER_BLOCK - 1) / ATOMS_PER_BLOCK), dim3(320), 0, stream>>>(
        hv_in, batch, mol, N_ATOMS);

    // 4) ffn [scalar f32]
    gemm_fused<false><<<gM, blk, 0, stream>>>(
        mol, f1W, HIDDEN, f1b, ffnh, N_MOLS, HIDDEN, HIDDEN, 1);
    gemm_fused<false><<<gO, blk, 0, stream>>>(
        ffnh, f2W, HIDDEN, f2b, (float*)d_out, N_MOLS, N_LABELS, N_LABELS, 0);
}

// Round 9
// 1774.755 us; speedup vs baseline: 2.9923x; 1.0285x over previous
//
#include <hip/hip_runtime.h>

#define N_ATOMS 100000
#define N_EDGES 400000
#define N_MOLS  4096
#define ATOM_FDIM 133
#define BOND_FDIM 14
#define HIDDEN 300
#define DEPTH 3
#define N_LABELS 12

#define KPAD 320          // row stride for bf16 activation buffers (and Wt k-stride)
#define XKP  192          // padded K for atom-embed input x (133 -> 192, /64)

#define BM 64
#define BN 64
#define BK 16

typedef unsigned short bf16_t;
typedef __bf16 bf16x8_t __attribute__((ext_vector_type(8)));
typedef float f32x4_t __attribute__((ext_vector_type(4)));

__device__ __forceinline__ float bf2f(bf16_t h) {
    return __uint_as_float(((unsigned int)h) << 16);
}
__device__ __forceinline__ bf16_t f2bf(float f) {
    unsigned int u = __float_as_uint(f);
    u = u + 0x7FFFu + ((u >> 16) & 1u);   // round-to-nearest-even
    return (bf16_t)(u >> 16);
}

// ---------------- scalar GEMM (ffn only: tiny M) ----------------
template<bool CBF>
__global__ __launch_bounds__(256) void gemm_fused(
    const float* __restrict__ A1, const float* __restrict__ W1, int K1,
    const float* __restrict__ bias, void* __restrict__ Cv,
    int M, int N, int ldc, int do_relu)
{
    __shared__ __align__(16) float As[BK][BM + 4];
    __shared__ __align__(16) float Bs[BK][BN];
    const int t  = threadIdx.x;
    const int tx = t & 15;
    const int ty = t >> 4;
    const int m0 = blockIdx.x * BM;
    const int n0 = blockIdx.y * BN;

    const int lr = t >> 2;
    const int lk = (t & 3) * 4;
    const int bk = t >> 4;
    const int bn = (t & 15) * 4;

    float acc[4][4] = {};
    const int K = K1;
    const bool k4 = ((K & 3) == 0);

    for (int k0 = 0; k0 < K; k0 += BK) {
        {
            const int row = m0 + lr;
            const int kbase = k0 + lk;
            float v0 = 0.f, v1 = 0.f, v2 = 0.f, v3 = 0.f;
            if (row < M) {
                const float* ap = A1 + (size_t)row * K;
                if (k4 && (kbase + 3 < K)) {
                    float4 v = *reinterpret_cast<const float4*>(ap + kbase);
                    v0 = v.x; v1 = v.y; v2 = v.z; v3 = v.w;
                } else {
                    if (kbase + 0 < K) v0 = ap[kbase + 0];
                    if (kbase + 1 < K) v1 = ap[kbase + 1];
                    if (kbase + 2 < K) v2 = ap[kbase + 2];
                    if (kbase + 3 < K) v3 = ap[kbase + 3];
                }
            }
            As[lk + 0][lr] = v0;
            As[lk + 1][lr] = v1;
            As[lk + 2][lr] = v2;
            As[lk + 3][lr] = v3;
        }
        {
            const int kk = k0 + bk;
            float v0 = 0.f, v1 = 0.f, v2 = 0.f, v3 = 0.f;
            if (kk < K) {
                const int nbase = n0 + bn;
                if (nbase + 3 < N) {
                    float4 v = *reinterpret_cast<const float4*>(W1 + (size_t)kk * N + nbase);
                    v0 = v.x; v1 = v.y; v2 = v.z; v3 = v.w;
                } else {
                    const float* wp = W1 + (size_t)kk * N;
                    if (nbase + 0 < N) v0 = wp[nbase + 0];
                    if (nbase + 1 < N) v1 = wp[nbase + 1];
                    if (nbase + 2 < N) v2 = wp[nbase + 2];
                    if (nbase + 3 < N) v3 = wp[nbase + 3];
                }
            }
            Bs[bk][bn + 0] = v0;
            Bs[bk][bn + 1] = v1;
            Bs[bk][bn + 2] = v2;
            Bs[bk][bn + 3] = v3;
        }
        __syncthreads();
        #pragma unroll
        for (int k = 0; k < BK; ++k) {
            float4 a = *reinterpret_cast<const float4*>(&As[k][ty * 4]);
            float4 b = *reinterpret_cast<const float4*>(&Bs[k][tx * 4]);
            float av[4] = {a.x, a.y, a.z, a.w};
            float bv[4] = {b.x, b.y, b.z, b.w};
            #pragma unroll
            for (int i = 0; i < 4; ++i)
                #pragma unroll
                for (int j = 0; j < 4; ++j)
                    acc[i][j] = fmaf(av[i], bv[j], acc[i][j]);
        }
        __syncthreads();
    }

    #pragma unroll
    for (int i = 0; i < 4; ++i) {
        const int row = m0 + ty * 4 + i;
        if (row >= M) continue;
        #pragma unroll
        for (int j = 0; j < 4; ++j) {
            const int col = n0 + tx * 4 + j;
            if (col >= N) continue;
            float v = acc[i][j];
            if (bias) v += bias[col];
            if (do_relu) v = fmaxf(v, 0.f);
            if (CBF) ((bf16_t*)Cv)[(size_t)row * ldc + col] = f2bf(v);
            else     ((float*)Cv)[(size_t)row * ldc + col] = v;
        }
    }
}

// ---- weight convert: W f32 [K,N] -> Wt bf16 [320 rows n][lda cols k], zero-pad ----
__global__ void convert_wt(const float* __restrict__ W, bf16_t* __restrict__ Wt,
                           int K, int N, int lda) {
    int idx = blockIdx.x * blockDim.x + threadIdx.x;
    if (idx >= 320 * lda) return;
    int n = idx / lda, k = idx % lda;
    float v = (k < K && n < N) ? W[(size_t)k * N + n] : 0.f;
    Wt[idx] = f2bf(v);
}

// ---- x f32 [N_ATOMS,133] -> bf16 [N_ATOMS, XKP], zero-pad ----
__global__ void convert_x(const float* __restrict__ x, bf16_t* __restrict__ xb) {
    int i = blockIdx.x * blockDim.x + threadIdx.x;
    if (i >= N_ATOMS * XKP) return;
    int r = i / XKP, k = i % XKP;
    xb[i] = f2bf(k < ATOM_FDIM ? x[(size_t)r * ATOM_FDIM + k] : 0.f);
}

// ---------------- MFMA GEMM v2: BK=64, 1D grid + bijective XCD swizzle --------
// C[M,300](bf16, ldc=KPAD) = [relu]( A1@W1 (+ A2@W2) (+ bias) )
// A: bf16 [M, LDA]; Wt: bf16 [320][LDA], Wt[n][k] = W[k][n], k-pad 0.
// Tile 128x64, 4 waves (2m x 2n); per k-step (64) each wave does 16 MFMAs.
#define MT_BM 128
#define MT_BN 64
#define MT_BK 64
#define ALD2 72           // LDS row stride in bf16 (64 + 8 pad)
#define MT_NB 5           // N tiles = KPAD / MT_BN

template<bool DUAL, int KMAX, int LDA>
__global__ __launch_bounds__(256) void gemm_mfma(
    const bf16_t* __restrict__ A1, const bf16_t* __restrict__ Wt1,
    const bf16_t* __restrict__ A2, const bf16_t* __restrict__ Wt2,
    const float* __restrict__ bias, bf16_t* __restrict__ C,
    int M, int do_relu)
{
    __shared__ __align__(16) bf16_t Alds[MT_BM][ALD2];   // 18.4 KB
    __shared__ __align__(16) bf16_t Blds[MT_BN][ALD2];   // 9.2 KB
    const int t = threadIdx.x;
    const int lane = t & 63;
    const int wave = t >> 6;
    const int wm = wave >> 1;
    const int wn = wave & 1;

    // bijective chunked XCD swizzle (m204): consecutive wg share the A panel
    int bid = blockIdx.x;
    {
        const int total = gridDim.x;
        const int q = total >> 3, r = total & 7;
        const int xcd = bid & 7, pos = bid >> 3;
        const int base = (xcd < r) ? xcd * (q + 1) : r * (q + 1) + (xcd - r) * q;
        bid = base + pos;
    }
    const int m0 = (bid / MT_NB) * MT_BM;
    const int n0 = (bid % MT_NB) * MT_BN;

    const int fr = lane & 15;
    const int kg = lane >> 4;

    f32x4_t acc[4][2];
    #pragma unroll
    for (int i = 0; i < 4; ++i)
        #pragma unroll
        for (int j = 0; j < 2; ++j)
            acc[i][j] = f32x4_t{0.f, 0.f, 0.f, 0.f};

    const int NPH = DUAL ? 2 : 1;
    for (int ph = 0; ph < NPH; ++ph) {
        const bf16_t* __restrict__ A  = ph ? A2  : A1;
        const bf16_t* __restrict__ Wt = ph ? Wt2 : Wt1;

        for (int k0 = 0; k0 < KMAX; k0 += MT_BK) {
            // stage A: 128 rows x 64 bf16 = 1024 16B-chunks, 4/thread
            #pragma unroll
            for (int cc = 0; cc < 4; ++cc) {
                const int c = t + cc * 256;
                const int row = c >> 3;            // 8 chunks per 64-elem row
                const int cid = c & 7;
                uint4 v = *reinterpret_cast<const uint4*>(
                    A + (size_t)(m0 + row) * LDA + k0 + cid * 8);
                *reinterpret_cast<uint4*>(&Alds[row][cid * 8]) = v;
            }
            // stage B: 64 rows x 64 bf16 = 512 chunks, 2/thread
            #pragma unroll
            for (int cc = 0; cc < 2; ++cc) {
                const int c = t + cc * 256;
                const int row = c >> 3;
                const int cid = c & 7;
                uint4 v = *reinterpret_cast<const uint4*>(
                    Wt + (size_t)(n0 + row) * LDA + k0 + cid * 8);
                *reinterpret_cast<uint4*>(&Blds[row][cid * 8]) = v;
            }
            __syncthreads();

            #pragma unroll
            for (int kk = 0; kk < 2; ++kk) {
                bf16x8_t af[4], bfr[2];
                #pragma unroll
                for (int i = 0; i < 4; ++i)
                    af[i] = *reinterpret_cast<const bf16x8_t*>(
                        &Alds[wm * 64 + i * 16 + fr][kk * 32 + kg * 8]);
                #pragma unroll
                for (int j = 0; j < 2; ++j)
                    bfr[j] = *reinterpret_cast<const bf16x8_t*>(
                        &Blds[wn * 32 + j * 16 + fr][kk * 32 + kg * 8]);
                #pragma unroll
                for (int i = 0; i < 4; ++i)
                    #pragma unroll
                    for (int j = 0; j < 2; ++j)
                        acc[i][j] = __builtin_amdgcn_mfma_f32_16x16x32_bf16(
                            af[i], bfr[j], acc[i][j], 0, 0, 0);
            }
            __syncthreads();
        }
    }

    #pragma unroll
    for (int j = 0; j < 2; ++j) {
        const int col = n0 + wn * 32 + j * 16 + fr;
        if (col >= HIDDEN) continue;
        const float bb = bias ? bias[col] : 0.f;
        #pragma unroll
        for (int i = 0; i < 4; ++i) {
            const int rbase = m0 + wm * 64 + i * 16 + kg * 4;
            #pragma unroll
            for (int q = 0; q < 4; ++q) {
                const int row = rbase + q;
                if (row >= M) continue;
                float v = acc[i][j][q] + bb;
                if (do_relu) v = fmaxf(v, 0.f);
                C[(size_t)row * KPAD + col] = f2bf(v);
            }
        }
    }
}

// ---------------- CSR build over dst ----------------
__global__ void csr_hist(const int* __restrict__ dst, int* __restrict__ cnt, int n) {
    int i = blockIdx.x * blockDim.x + threadIdx.x;
    if (i < n) atomicAdd(&cnt[dst[i]], 1);
}

#define SCAN_T 1024
__global__ __launch_bounds__(SCAN_T) void csr_scan(
    const int* __restrict__ cnt, int* __restrict__ row_ptr) {
    __shared__ int sums[SCAN_T];
    const int t = threadIdx.x;
    const int per = (N_ATOMS + SCAN_T - 1) / SCAN_T;
    const int base = t * per;
    int local = 0;
    for (int i = 0; i < per; ++i) {
        int idx = base + i;
        if (idx < N_ATOMS) local += cnt[idx];
    }
    sums[t] = local;
    __syncthreads();
    for (int off = 1; off < SCAN_T; off <<= 1) {
        int v = (t >= off) ? sums[t - off] : 0;
        __syncthreads();
        if (t >= off) sums[t] += v;
        __syncthreads();
    }
    int prefix = (t == 0) ? 0 : sums[t - 1];
    for (int i = 0; i < per; ++i) {
        int idx = base + i;
        if (idx < N_ATOMS) {
            row_ptr[idx] = prefix;
            prefix += cnt[idx];
        }
    }
    if (t == SCAN_T - 1) row_ptr[N_ATOMS] = prefix;
}

__global__ void csr_fill(const int* __restrict__ dst, int* __restrict__ pos,
                         int* __restrict__ eid, int n) {
    int i = blockIdx.x * blockDim.x + threadIdx.x;
    if (i < n) {
        int p = atomicAdd(&pos[dst[i]], 1);
        eid[p] = i;
    }
}

// ---- agg[v] = sum_{e: dst=v} relu(hW[src_e] + ea_e @ WiB), bf16 out ----
// v4: window of 4 edges; ALL 20 row loads + 28 ea loads issued before any FMA
// (one latency wall per window instead of per edge -> ~4x MLP).
#define LOADH(H, R) \
    const bf16_t H##0 = (R)[lane]; \
    const bf16_t H##1 = (R)[lane + 64]; \
    const bf16_t H##2 = (R)[lane + 128]; \
    const bf16_t H##3 = (R)[lane + 192]; \
    const bf16_t H##4 = (lane < 44) ? (R)[lane + 256] : (bf16_t)0;

#define LOADEA(EA, E) { \
    const float* ep_ = edge_attr + (size_t)(E) * BOND_FDIM; \
    _Pragma("unroll") \
    for (int q_ = 0; q_ < 7; ++q_) { \
        float2 w2_ = *reinterpret_cast<const float2*>(ep_ + 2 * q_); \
        EA[2 * q_] = w2_.x; EA[2 * q_ + 1] = w2_.y; } }

#define ACC_EDGE(EA, H) { \
    float m0 = bf2f(H##0), m1 = bf2f(H##1), m2 = bf2f(H##2), m3 = bf2f(H##3), m4 = bf2f(H##4); \
    _Pragma("unroll") \
    for (int k_ = 0; k_ < BOND_FDIM; ++k_) { \
        const float* wk_ = &sWiB[k_ * HIDDEN]; \
        const float ek_ = EA[k_]; \
        m0 = fmaf(ek_, wk_[lane], m0); \
        m1 = fmaf(ek_, wk_[lane + 64], m1); \
        m2 = fmaf(ek_, wk_[lane + 128], m2); \
        m3 = fmaf(ek_, wk_[lane + 192], m3); \
        if (lane < 44) m4 = fmaf(ek_, wk_[lane + 256], m4); } \
    acc0 += fmaxf(m0, 0.f); acc1 += fmaxf(m1, 0.f); acc2 += fmaxf(m2, 0.f); \
    acc3 += fmaxf(m3, 0.f); acc4 += fmaxf(m4, 0.f); }

__global__ __launch_bounds__(256) void gather_agg(
    const bf16_t* __restrict__ hW, const float* __restrict__ edge_attr,
    const int* __restrict__ src, const int* __restrict__ row_ptr,
    const int* __restrict__ eid, const float* __restrict__ WiB,
    bf16_t* __restrict__ agg)
{
    __shared__ __align__(16) float sWiB[BOND_FDIM * HIDDEN];   // 16.8 KB
    const int t = threadIdx.x;
    for (int i = t; i < BOND_FDIM * HIDDEN; i += 256) sWiB[i] = WiB[i];
    __syncthreads();

    const int wave = t >> 6;
    const int lane = t & 63;
    const int vbase = blockIdx.x * 16 + wave * 4;

    #pragma unroll 1
    for (int a = 0; a < 4; ++a) {
        const int v = vbase + a;
        if (v >= N_ATOMS) return;
        const int beg = row_ptr[v];
        const int end = row_ptr[v + 1];

        float acc0 = 0.f, acc1 = 0.f, acc2 = 0.f, acc3 = 0.f, acc4 = 0.f;

        #pragma unroll 1
        for (int base = beg; base < end; base += 4) {
            const int n = end - base;
            // resolve indices (inactive slots clamp to edge 0 of the window)
            const int i1 = (n > 1) ? base + 1 : base;
            const int i2 = (n > 2) ? base + 2 : base;
            const int i3 = (n > 3) ? base + 3 : base;
            const int e0 = eid[base], e1 = eid[i1], e2 = eid[i2], e3 = eid[i3];
            const int s0 = src[e0], s1 = src[e1], s2 = src[e2], s3 = src[e3];
            const bf16_t* __restrict__ r0 = hW + (size_t)s0 * KPAD;
            const bf16_t* __restrict__ r1 = hW + (size_t)s1 * KPAD;
            const bf16_t* __restrict__ r2 = hW + (size_t)s2 * KPAD;
            const bf16_t* __restrict__ r3 = hW + (size_t)s3 * KPAD;
            // issue ALL row loads
            LOADH(hA, r0) LOADH(hB, r1) LOADH(hC, r2) LOADH(hD, r3)
            // issue ALL edge_attr loads
            float ea0[BOND_FDIM], ea1[BOND_FDIM], ea2[BOND_FDIM], ea3[BOND_FDIM];
            LOADEA(ea0, e0)
            if (n > 1) LOADEA(ea1, e1)
            if (n > 2) LOADEA(ea2, e2)
            if (n > 3) LOADEA(ea3, e3)
            // accumulate
            ACC_EDGE(ea0, hA)
            if (n > 1) ACC_EDGE(ea1, hB)
            if (n > 2) ACC_EDGE(ea2, hC)
            if (n > 3) ACC_EDGE(ea3, hD)
        }
        bf16_t* __restrict__ arow = agg + (size_t)v * KPAD;
        arow[lane]       = f2bf(acc0);
        arow[lane + 64]  = f2bf(acc1);
        arow[lane + 128] = f2bf(acc2);
        arow[lane + 192] = f2bf(acc3);
        if (lane < 44) arow[lane + 256] = f2bf(acc4);
    }
}

// Segment-sum of bf16 h_v (stride KPAD) into fp32 mol_repr (batch sorted).
#define ATOMS_PER_BLOCK 32
__global__ __launch_bounds__(320) void mol_reduce(
    const bf16_t* __restrict__ hv, const int* __restrict__ batch,
    float* __restrict__ mol, int n_atoms)
{
    const int j = threadIdx.x;
    if (j >= HIDDEN) return;
    const int a0 = blockIdx.x * ATOMS_PER_BLOCK;
    const int aend = min(a0 + ATOMS_PER_BLOCK, n_atoms);
    float acc = 0.f;
    int cur = batch[a0];
    for (int a = a0; a < aend; ++a) {
        const int b = batch[a];
        if (b != cur) {
            atomicAdd(&mol[(size_t)cur * HIDDEN + j], acc);
            acc = 0.f;
            cur = b;
        }
        acc += bf2f(hv[(size_t)a * KPAD + j]);
    }
    atomicAdd(&mol[(size_t)cur * HIDDEN + j], acc);
}

__global__ void fill_const(float* p, int n, float v) {
    int i = blockIdx.x * blockDim.x + threadIdx.x;
    if (i < n) p[i] = v;
}

static inline size_t align256(size_t x) { return (x + 255) & ~(size_t)255; }

extern "C" void kernel_launch(void* const* d_in, const int* in_sizes, int n_in,
                              void* d_out, int out_size, void* d_ws, size_t ws_size,
                              hipStream_t stream) {
    const float* x       = (const float*)d_in[0];
    const int*   ei      = (const int*)  d_in[1];
    const float* ea      = (const float*)d_in[2];
    const int*   batch   = (const int*)  d_in[3];
    const float* atom_W  = (const float*)d_in[4];
    const float* atom_b  = (const float*)d_in[5];
    // d_in[6] bond_W, d_in[7] bond_b, d_in[9] Wh: dead code
    const float* Wi      = (const float*)d_in[8];    // [314,300]
    const float* Wo      = (const float*)d_in[10];   // [600,300]
    const float* Wo_b    = (const float*)d_in[11];
    const float* f1W     = (const float*)d_in[12];
    const float* f1b     = (const float*)d_in[13];
    const float* f2W     = (const float*)d_in[14];
    const float* f2b     = (const float*)d_in[15];

    const int* src = ei;            // edge_index[0]
    const int* dst = ei + N_EDGES;  // edge_index[1]

    const float* Wi_top = Wi;                            // [300,300]
    const float* WiB    = Wi + (size_t)HIDDEN * HIDDEN;  // [14,300]
    const float* Wo_top = Wo;                            // [300,300]
    const float* Wo_bot = Wo + (size_t)HIDDEN * HIDDEN;  // [300,300]

    // ---- workspace ----
    const size_t hv_b   = (size_t)N_ATOMS * KPAD * sizeof(bf16_t);  // 64 MB
    const size_t xb_b   = (size_t)N_ATOMS * XKP  * sizeof(bf16_t);  // 38.4 MB
    const size_t wt_b   = (size_t)320 * KPAD * sizeof(bf16_t);      // 200 KB
    const size_t wta_b  = (size_t)320 * XKP  * sizeof(bf16_t);      // 120 KB
    const size_t mol_f  = (size_t)N_MOLS * HIDDEN * sizeof(float);  // 4.9 MB
    const size_t rp_b   = (size_t)(N_ATOMS + 1) * sizeof(int);
    const size_t cnt_b  = (size_t)N_ATOMS * sizeof(int);
    const size_t eid_b  = (size_t)N_EDGES * sizeof(int);
    const size_t needed = 3 * align256(hv_b) + align256(xb_b)
                        + 3 * align256(wt_b) + align256(wta_b)
                        + 2 * align256(mol_f)
                        + align256(rp_b) + align256(cnt_b) + align256(eid_b)
                        + 65536;   // slack for benign OOB-row staging reads
    if (ws_size < needed) {
        fill_const<<<dim3((out_size + 255) / 256), dim3(256), 0, stream>>>(
            (float*)d_out, out_size, 1.0e6f);   // canary: ws too small
        return;
    }
    char* p = (char*)d_ws;
    bf16_t* bufA   = (bf16_t*)p; p += align256(hv_b);    // hv ping
    bf16_t* bufB   = (bf16_t*)p; p += align256(hv_b);    // hW / hv_out (aliased)
    bf16_t* agg    = (bf16_t*)p; p += align256(hv_b);
    bf16_t* xb     = (bf16_t*)p; p += align256(xb_b);    // x in bf16, [N_ATOMS, XKP]
    bf16_t* Wt_i   = (bf16_t*)p; p += align256(wt_b);    // Wi_top^T
    bf16_t* Wt_o1  = (bf16_t*)p; p += align256(wt_b);    // Wo_top^T
    bf16_t* Wt_o2  = (bf16_t*)p; p += align256(wt_b);    // Wo_bot^T
    bf16_t* Wt_a   = (bf16_t*)p; p += align256(wta_b);   // atom_W^T [320][XKP]
    float*  mol    = (float*)p;  p += align256(mol_f);
    float*  ffnh   = (float*)p;  p += align256(mol_f);
    int*    row_ptr= (int*)p;    p += align256(rp_b);
    int*    cntpos = (int*)p;    p += align256(cnt_b);
    int*    eid    = (int*)p;    p += align256(eid_b);

    dim3 blk(256);
    dim3 gM((N_MOLS + BM - 1) / BM, (HIDDEN + BN - 1) / BN);
    dim3 gO((N_MOLS + BM - 1) / BM, (N_LABELS + BN - 1) / BN);
    dim3 gE((N_EDGES + 255) / 256);
    dim3 gW((320 * KPAD + 255) / 256);
    dim3 gWa((320 * XKP + 255) / 256);
    dim3 gX((N_ATOMS * XKP + 255) / 256);
    const int mfx = (N_ATOMS + MT_BM - 1) / MT_BM;              // 782
    dim3 gMF(mfx * MT_NB);                                      // 1D, swizzled in-kernel
    dim3 gGA((N_ATOMS + 15) / 16);                              // 6250

    // ---- one-time per call: converts + CSR ----
    convert_wt<<<gW,  blk, 0, stream>>>(Wi_top, Wt_i,  HIDDEN, HIDDEN, KPAD);
    convert_wt<<<gW,  blk, 0, stream>>>(Wo_top, Wt_o1, HIDDEN, HIDDEN, KPAD);
    convert_wt<<<gW,  blk, 0, stream>>>(Wo_bot, Wt_o2, HIDDEN, HIDDEN, KPAD);
    convert_wt<<<gWa, blk, 0, stream>>>(atom_W, Wt_a,  ATOM_FDIM, HIDDEN, XKP);
    convert_x<<<gX,   blk, 0, stream>>>(x, xb);

    hipMemsetAsync(cntpos, 0, cnt_b, stream);
    csr_hist<<<gE, blk, 0, stream>>>(dst, cntpos, N_EDGES);
    csr_scan<<<dim3(1), dim3(SCAN_T), 0, stream>>>(cntpos, row_ptr);
    hipMemcpyAsync(cntpos, row_ptr, cnt_b, hipMemcpyDeviceToDevice, stream);
    csr_fill<<<gE, blk, 0, stream>>>(dst, cntpos, eid, N_EDGES);

    // 1) h_v = relu(x @ atom_W + atom_b)   [MFMA, K=192]
    gemm_mfma<false, XKP, XKP><<<gMF, blk, 0, stream>>>(
        xb, Wt_a, nullptr, nullptr, atom_b, bufA, N_ATOMS, 1);

    bf16_t* hv_in   = bufA;
    bf16_t* scratch = bufB;   // holds hW, then hv_out
    for (int it = 0; it < DEPTH; ++it) {
        // 2a) hW = h_v @ Wi_top              [MFMA]
        gemm_mfma<false, KPAD, KPAD><<<gMF, blk, 0, stream>>>(
            hv_in, Wt_i, nullptr, nullptr, nullptr, scratch, N_ATOMS, 0);
        // 2b) agg = CSR-gather of relu(hW[src] + ea@WiB)
        gather_agg<<<gGA, blk, 0, stream>>>(
            scratch, ea, src, row_ptr, eid, WiB, agg);
        // 2c) h_v' = relu(h_v @ Wo_top + agg @ Wo_bot + Wo_b)   [MFMA dual]
        gemm_mfma<true, KPAD, KPAD><<<gMF, blk, 0, stream>>>(
            hv_in, Wt_o1, agg, Wt_o2, Wo_b, scratch, N_ATOMS, 1);
        bf16_t* tmp = hv_in; hv_in = scratch; scratch = tmp;
    }

    // 3) mol_repr = segment_sum(h_v, batch)
    hipMemsetAsync(mol, 0, mol_f, stream);
    mol_reduce<<<dim3((N_ATOMS + ATOMS_PER_BLOCK - 1) / ATOMS_PER_BLOCK), dim3(320), 0, stream>>>(
        hv_in, batch, mol, N_ATOMS);

    // 4) ffn [scalar f32]
    gemm_fused<false><<<gM, blk, 0, stream>>>(
        mol, f1W, HIDDEN, f1b, ffnh, N_MOLS, HIDDEN, HIDDEN, 1);
    gemm_fused<false><<<gO, blk, 0, stream>>>(
        ffnh, f2W, HIDDEN, f2b, (float*)d_out, N_MOLS, N_LABELS, N_LABELS, 0);
}

// Round 10
// 1732.021 us; speedup vs baseline: 3.0661x; 1.0247x over previous
//
#include <hip/hip_runtime.h>

#define N_ATOMS 100000
#define N_EDGES 400000
#define N_MOLS  4096
#define ATOM_FDIM 133
#define BOND_FDIM 14
#define HIDDEN 300
#define DEPTH 3
#define N_LABELS 12

#define KPAD 320          // row stride for bf16 activation buffers (and Wt k-stride)
#define XKP  192          // padded K for atom-embed input x (133 -> 192, /64)

#define BM 64
#define BN 64
#define BK 16

typedef unsigned short bf16_t;
typedef __bf16 bf16x8_t __attribute__((ext_vector_type(8)));
typedef float f32x4_t __attribute__((ext_vector_type(4)));

__device__ __forceinline__ float bf2f(bf16_t h) {
    return __uint_as_float(((unsigned int)h) << 16);
}
__device__ __forceinline__ bf16_t f2bf(float f) {
    unsigned int u = __float_as_uint(f);
    u = u + 0x7FFFu + ((u >> 16) & 1u);   // round-to-nearest-even
    return (bf16_t)(u >> 16);
}

// ---------------- scalar GEMM (ffn only: tiny M) ----------------
template<bool CBF>
__global__ __launch_bounds__(256) void gemm_fused(
    const float* __restrict__ A1, const float* __restrict__ W1, int K1,
    const float* __restrict__ bias, void* __restrict__ Cv,
    int M, int N, int ldc, int do_relu)
{
    __shared__ __align__(16) float As[BK][BM + 4];
    __shared__ __align__(16) float Bs[BK][BN];
    const int t  = threadIdx.x;
    const int tx = t & 15;
    const int ty = t >> 4;
    const int m0 = blockIdx.x * BM;
    const int n0 = blockIdx.y * BN;

    const int lr = t >> 2;
    const int lk = (t & 3) * 4;
    const int bk = t >> 4;
    const int bn = (t & 15) * 4;

    float acc[4][4] = {};
    const int K = K1;
    const bool k4 = ((K & 3) == 0);

    for (int k0 = 0; k0 < K; k0 += BK) {
        {
            const int row = m0 + lr;
            const int kbase = k0 + lk;
            float v0 = 0.f, v1 = 0.f, v2 = 0.f, v3 = 0.f;
            if (row < M) {
                const float* ap = A1 + (size_t)row * K;
                if (k4 && (kbase + 3 < K)) {
                    float4 v = *reinterpret_cast<const float4*>(ap + kbase);
                    v0 = v.x; v1 = v.y; v2 = v.z; v3 = v.w;
                } else {
                    if (kbase + 0 < K) v0 = ap[kbase + 0];
                    if (kbase + 1 < K) v1 = ap[kbase + 1];
                    if (kbase + 2 < K) v2 = ap[kbase + 2];
                    if (kbase + 3 < K) v3 = ap[kbase + 3];
                }
            }
            As[lk + 0][lr] = v0;
            As[lk + 1][lr] = v1;
            As[lk + 2][lr] = v2;
            As[lk + 3][lr] = v3;
        }
        {
            const int kk = k0 + bk;
            float v0 = 0.f, v1 = 0.f, v2 = 0.f, v3 = 0.f;
            if (kk < K) {
                const int nbase = n0 + bn;
                if (nbase + 3 < N) {
                    float4 v = *reinterpret_cast<const float4*>(W1 + (size_t)kk * N + nbase);
                    v0 = v.x; v1 = v.y; v2 = v.z; v3 = v.w;
                } else {
                    const float* wp = W1 + (size_t)kk * N;
                    if (nbase + 0 < N) v0 = wp[nbase + 0];
                    if (nbase + 1 < N) v1 = wp[nbase + 1];
                    if (nbase + 2 < N) v2 = wp[nbase + 2];
                    if (nbase + 3 < N) v3 = wp[nbase + 3];
                }
            }
            Bs[bk][bn + 0] = v0;
            Bs[bk][bn + 1] = v1;
            Bs[bk][bn + 2] = v2;
            Bs[bk][bn + 3] = v3;
        }
        __syncthreads();
        #pragma unroll
        for (int k = 0; k < BK; ++k) {
            float4 a = *reinterpret_cast<const float4*>(&As[k][ty * 4]);
            float4 b = *reinterpret_cast<const float4*>(&Bs[k][tx * 4]);
            float av[4] = {a.x, a.y, a.z, a.w};
            float bv[4] = {b.x, b.y, b.z, b.w};
            #pragma unroll
            for (int i = 0; i < 4; ++i)
                #pragma unroll
                for (int j = 0; j < 4; ++j)
                    acc[i][j] = fmaf(av[i], bv[j], acc[i][j]);
        }
        __syncthreads();
    }

    #pragma unroll
    for (int i = 0; i < 4; ++i) {
        const int row = m0 + ty * 4 + i;
        if (row >= M) continue;
        #pragma unroll
        for (int j = 0; j < 4; ++j) {
            const int col = n0 + tx * 4 + j;
            if (col >= N) continue;
            float v = acc[i][j];
            if (bias) v += bias[col];
            if (do_relu) v = fmaxf(v, 0.f);
            if (CBF) ((bf16_t*)Cv)[(size_t)row * ldc + col] = f2bf(v);
            else     ((float*)Cv)[(size_t)row * ldc + col] = v;
        }
    }
}

// ---- weight convert: W f32 [K,N] -> Wt bf16 [320 rows n][lda cols k], zero-pad ----
__global__ void convert_wt(const float* __restrict__ W, bf16_t* __restrict__ Wt,
                           int K, int N, int lda) {
    int idx = blockIdx.x * blockDim.x + threadIdx.x;
    if (idx >= 320 * lda) return;
    int n = idx / lda, k = idx % lda;
    float v = (k < K && n < N) ? W[(size_t)k * N + n] : 0.f;
    Wt[idx] = f2bf(v);
}

// ---- x f32 [N_ATOMS,133] -> bf16 [N_ATOMS, XKP], zero-pad ----
__global__ void convert_x(const float* __restrict__ x, bf16_t* __restrict__ xb) {
    int i = blockIdx.x * blockDim.x + threadIdx.x;
    if (i >= N_ATOMS * XKP) return;
    int r = i / XKP, k = i % XKP;
    xb[i] = f2bf(k < ATOM_FDIM ? x[(size_t)r * ATOM_FDIM + k] : 0.f);
}

// ---------------- MFMA GEMM v2: BK=64, 1D grid + bijective XCD swizzle --------
#define MT_BM 128
#define MT_BN 64
#define MT_BK 64
#define ALD2 72           // LDS row stride in bf16 (64 + 8 pad)
#define MT_NB 5           // N tiles = KPAD / MT_BN

template<bool DUAL, int KMAX, int LDA>
__global__ __launch_bounds__(256) void gemm_mfma(
    const bf16_t* __restrict__ A1, const bf16_t* __restrict__ Wt1,
    const bf16_t* __restrict__ A2, const bf16_t* __restrict__ Wt2,
    const float* __restrict__ bias, bf16_t* __restrict__ C,
    int M, int do_relu)
{
    __shared__ __align__(16) bf16_t Alds[MT_BM][ALD2];   // 18.4 KB
    __shared__ __align__(16) bf16_t Blds[MT_BN][ALD2];   // 9.2 KB
    const int t = threadIdx.x;
    const int lane = t & 63;
    const int wave = t >> 6;
    const int wm = wave >> 1;
    const int wn = wave & 1;

    // bijective chunked XCD swizzle (m204)
    int bid = blockIdx.x;
    {
        const int total = gridDim.x;
        const int q = total >> 3, r = total & 7;
        const int xcd = bid & 7, pos = bid >> 3;
        const int base = (xcd < r) ? xcd * (q + 1) : r * (q + 1) + (xcd - r) * q;
        bid = base + pos;
    }
    const int m0 = (bid / MT_NB) * MT_BM;
    const int n0 = (bid % MT_NB) * MT_BN;

    const int fr = lane & 15;
    const int kg = lane >> 4;

    f32x4_t acc[4][2];
    #pragma unroll
    for (int i = 0; i < 4; ++i)
        #pragma unroll
        for (int j = 0; j < 2; ++j)
            acc[i][j] = f32x4_t{0.f, 0.f, 0.f, 0.f};

    const int NPH = DUAL ? 2 : 1;
    for (int ph = 0; ph < NPH; ++ph) {
        const bf16_t* __restrict__ A  = ph ? A2  : A1;
        const bf16_t* __restrict__ Wt = ph ? Wt2 : Wt1;

        for (int k0 = 0; k0 < KMAX; k0 += MT_BK) {
            #pragma unroll
            for (int cc = 0; cc < 4; ++cc) {
                const int c = t + cc * 256;
                const int row = c >> 3;
                const int cid = c & 7;
                uint4 v = *reinterpret_cast<const uint4*>(
                    A + (size_t)(m0 + row) * LDA + k0 + cid * 8);
                *reinterpret_cast<uint4*>(&Alds[row][cid * 8]) = v;
            }
            #pragma unroll
            for (int cc = 0; cc < 2; ++cc) {
                const int c = t + cc * 256;
                const int row = c >> 3;
                const int cid = c & 7;
                uint4 v = *reinterpret_cast<const uint4*>(
                    Wt + (size_t)(n0 + row) * LDA + k0 + cid * 8);
                *reinterpret_cast<uint4*>(&Blds[row][cid * 8]) = v;
            }
            __syncthreads();

            #pragma unroll
            for (int kk = 0; kk < 2; ++kk) {
                bf16x8_t af[4], bfr[2];
                #pragma unroll
                for (int i = 0; i < 4; ++i)
                    af[i] = *reinterpret_cast<const bf16x8_t*>(
                        &Alds[wm * 64 + i * 16 + fr][kk * 32 + kg * 8]);
                #pragma unroll
                for (int j = 0; j < 2; ++j)
                    bfr[j] = *reinterpret_cast<const bf16x8_t*>(
                        &Blds[wn * 32 + j * 16 + fr][kk * 32 + kg * 8]);
                #pragma unroll
                for (int i = 0; i < 4; ++i)
                    #pragma unroll
                    for (int j = 0; j < 2; ++j)
                        acc[i][j] = __builtin_amdgcn_mfma_f32_16x16x32_bf16(
                            af[i], bfr[j], acc[i][j], 0, 0, 0);
            }
            __syncthreads();
        }
    }

    #pragma unroll
    for (int j = 0; j < 2; ++j) {
        const int col = n0 + wn * 32 + j * 16 + fr;
        if (col >= HIDDEN) continue;
        const float bb = bias ? bias[col] : 0.f;
        #pragma unroll
        for (int i = 0; i < 4; ++i) {
            const int rbase = m0 + wm * 64 + i * 16 + kg * 4;
            #pragma unroll
            for (int q = 0; q < 4; ++q) {
                const int row = rbase + q;
                if (row >= M) continue;
                float v = acc[i][j][q] + bb;
                if (do_relu) v = fmaxf(v, 0.f);
                C[(size_t)row * KPAD + col] = f2bf(v);
            }
        }
    }
}

// ---------------- CSR build over dst ----------------
__global__ void csr_hist(const int* __restrict__ dst, int* __restrict__ cnt, int n) {
    int i = blockIdx.x * blockDim.x + threadIdx.x;
    if (i < n) atomicAdd(&cnt[dst[i]], 1);
}

#define SCAN_T 1024
__global__ __launch_bounds__(SCAN_T) void csr_scan(
    const int* __restrict__ cnt, int* __restrict__ row_ptr) {
    __shared__ int sums[SCAN_T];
    const int t = threadIdx.x;
    const int per = (N_ATOMS + SCAN_T - 1) / SCAN_T;
    const int base = t * per;
    int local = 0;
    for (int i = 0; i < per; ++i) {
        int idx = base + i;
        if (idx < N_ATOMS) local += cnt[idx];
    }
    sums[t] = local;
    __syncthreads();
    for (int off = 1; off < SCAN_T; off <<= 1) {
        int v = (t >= off) ? sums[t - off] : 0;
        __syncthreads();
        if (t >= off) sums[t] += v;
        __syncthreads();
    }
    int prefix = (t == 0) ? 0 : sums[t - 1];
    for (int i = 0; i < per; ++i) {
        int idx = base + i;
        if (idx < N_ATOMS) {
            row_ptr[idx] = prefix;
            prefix += cnt[idx];
        }
    }
    if (t == SCAN_T - 1) row_ptr[N_ATOMS] = prefix;
}

__global__ void csr_fill(const int* __restrict__ dst, int* __restrict__ pos,
                         int* __restrict__ eid, int n) {
    int i = blockIdx.x * blockDim.x + threadIdx.x;
    if (i < n) {
        int p = atomicAdd(&pos[dst[i]], 1);
        eid[p] = i;
    }
}

// ---- agg[v] = sum_{e: dst=v} relu(hW[src_e] + ea_e @ WiB), bf16 out ----
// v5: HALF-WAVE per atom (2 independent edge streams per wave), 512-thr blocks,
// ushort2 col-pair loads (5 x 128B coalesced requests/row), sWiB padded [14][320]
// in LDS as float2 (2-way alias = free), no column guards (junk cols harmless:
// they hit zero rows of Wt_o2 downstream). 2-deep (eid,src) prefetch kept.
__global__ __launch_bounds__(512) void gather_agg(
    const bf16_t* __restrict__ hW, const float* __restrict__ edge_attr,
    const int* __restrict__ src, const int* __restrict__ row_ptr,
    const int* __restrict__ eid, const float* __restrict__ WiB,
    bf16_t* __restrict__ agg)
{
    __shared__ __align__(16) float sWiB[BOND_FDIM * KPAD];   // 17.9 KB, zero-padded
    const int t = threadIdx.x;
    for (int i = t; i < BOND_FDIM * KPAD; i += 512) {
        const int k = i / KPAD, j = i % KPAD;
        sWiB[i] = (j < HIDDEN) ? WiB[k * HIDDEN + j] : 0.f;
    }
    __syncthreads();

    const int wave = t >> 6;
    const int half = (t >> 5) & 1;
    const int l32  = t & 31;
    const int v = blockIdx.x * 16 + wave * 2 + half;
    if (v >= N_ATOMS) return;

    const int beg = row_ptr[v];
    const int end = row_ptr[v + 1];

    // lane l32 owns col pairs (2*l32 + 64c, 2*l32+1 + 64c), c = 0..4
    const int cb = 2 * l32;

    float accx[5] = {0.f, 0.f, 0.f, 0.f, 0.f};
    float accy[5] = {0.f, 0.f, 0.f, 0.f, 0.f};

    int e_cur = 0, s_cur = 0;
    if (beg < end) { e_cur = eid[beg]; s_cur = src[e_cur]; }
    #pragma unroll 1
    for (int idx = beg; idx < end; ++idx) {
        const int e = e_cur, s = s_cur;
        if (idx + 1 < end) {                 // prefetch next edge's indices
            e_cur = eid[idx + 1];
            s_cur = src[e_cur];
        }
        const bf16_t* __restrict__ hrow = hW + (size_t)s * KPAD;
        ushort2 h[5];
        #pragma unroll
        for (int c = 0; c < 5; ++c)
            h[c] = *reinterpret_cast<const ushort2*>(hrow + cb + 64 * c);
        const float* __restrict__ ep = edge_attr + (size_t)e * BOND_FDIM;
        float eav[BOND_FDIM];
        #pragma unroll
        for (int q = 0; q < BOND_FDIM / 2; ++q) {
            float2 w2 = *reinterpret_cast<const float2*>(ep + 2 * q);
            eav[2 * q] = w2.x; eav[2 * q + 1] = w2.y;
        }
        #pragma unroll
        for (int c = 0; c < 5; ++c) {
            float mx = bf2f(h[c].x);
            float my = bf2f(h[c].y);
            #pragma unroll
            for (int k = 0; k < BOND_FDIM; ++k) {
                const float2 w = *reinterpret_cast<const float2*>(
                    &sWiB[k * KPAD + cb + 64 * c]);
                mx = fmaf(eav[k], w.x, mx);
                my = fmaf(eav[k], w.y, my);
            }
            accx[c] += fmaxf(mx, 0.f);
            accy[c] += fmaxf(my, 0.f);
        }
    }

    bf16_t* __restrict__ arow = agg + (size_t)v * KPAD;
    #pragma unroll
    for (int c = 0; c < 5; ++c) {
        ushort2 o;
        o.x = f2bf(accx[c]);
        o.y = f2bf(accy[c]);
        *reinterpret_cast<ushort2*>(arow + cb + 64 * c) = o;
    }
}

// Segment-sum of bf16 h_v (stride KPAD) into fp32 mol_repr (batch sorted).
#define ATOMS_PER_BLOCK 32
__global__ __launch_bounds__(320) void mol_reduce(
    const bf16_t* __restrict__ hv, const int* __restrict__ batch,
    float* __restrict__ mol, int n_atoms)
{
    const int j = threadIdx.x;
    if (j >= HIDDEN) return;
    const int a0 = blockIdx.x * ATOMS_PER_BLOCK;
    const int aend = min(a0 + ATOMS_PER_BLOCK, n_atoms);
    float acc = 0.f;
    int cur = batch[a0];
    for (int a = a0; a < aend; ++a) {
        const int b = batch[a];
        if (b != cur) {
            atomicAdd(&mol[(size_t)cur * HIDDEN + j], acc);
            acc = 0.f;
            cur = b;
        }
        acc += bf2f(hv[(size_t)a * KPAD + j]);
    }
    atomicAdd(&mol[(size_t)cur * HIDDEN + j], acc);
}

__global__ void fill_const(float* p, int n, float v) {
    int i = blockIdx.x * blockDim.x + threadIdx.x;
    if (i < n) p[i] = v;
}

static inline size_t align256(size_t x) { return (x + 255) & ~(size_t)255; }

extern "C" void kernel_launch(void* const* d_in, const int* in_sizes, int n_in,
                              void* d_out, int out_size, void* d_ws, size_t ws_size,
                              hipStream_t stream) {
    const float* x       = (const float*)d_in[0];
    const int*   ei      = (const int*)  d_in[1];
    const float* ea      = (const float*)d_in[2];
    const int*   batch   = (const int*)  d_in[3];
    const float* atom_W  = (const float*)d_in[4];
    const float* atom_b  = (const float*)d_in[5];
    // d_in[6] bond_W, d_in[7] bond_b, d_in[9] Wh: dead code
    const float* Wi      = (const float*)d_in[8];    // [314,300]
    const float* Wo      = (const float*)d_in[10];   // [600,300]
    const float* Wo_b    = (const float*)d_in[11];
    const float* f1W     = (const float*)d_in[12];
    const float* f1b     = (const float*)d_in[13];
    const float* f2W     = (const float*)d_in[14];
    const float* f2b     = (const float*)d_in[15];

    const int* src = ei;            // edge_index[0]
    const int* dst = ei + N_EDGES;  // edge_index[1]

    const float* Wi_top = Wi;                            // [300,300]
    const float* WiB    = Wi + (size_t)HIDDEN * HIDDEN;  // [14,300]
    const float* Wo_top = Wo;                            // [300,300]
    const float* Wo_bot = Wo + (size_t)HIDDEN * HIDDEN;  // [300,300]

    // ---- workspace ----
    const size_t hv_b   = (size_t)N_ATOMS * KPAD * sizeof(bf16_t);  // 64 MB
    const size_t xb_b   = (size_t)N_ATOMS * XKP  * sizeof(bf16_t);  // 38.4 MB
    const size_t wt_b   = (size_t)320 * KPAD * sizeof(bf16_t);      // 200 KB
    const size_t wta_b  = (size_t)320 * XKP  * sizeof(bf16_t);      // 120 KB
    const size_t mol_f  = (size_t)N_MOLS * HIDDEN * sizeof(float);  // 4.9 MB
    const size_t rp_b   = (size_t)(N_ATOMS + 1) * sizeof(int);
    const size_t cnt_b  = (size_t)N_ATOMS * sizeof(int);
    const size_t eid_b  = (size_t)N_EDGES * sizeof(int);
    const size_t needed = 3 * align256(hv_b) + align256(xb_b)
                        + 3 * align256(wt_b) + align256(wta_b)
                        + 2 * align256(mol_f)
                        + align256(rp_b) + align256(cnt_b) + align256(eid_b)
                        + 65536;   // slack for benign OOB-row staging reads
    if (ws_size < needed) {
        fill_const<<<dim3((out_size + 255) / 256), dim3(256), 0, stream>>>(
            (float*)d_out, out_size, 1.0e6f);   // canary: ws too small
        return;
    }
    char* p = (char*)d_ws;
    bf16_t* bufA   = (bf16_t*)p; p += align256(hv_b);    // hv ping
    bf16_t* bufB   = (bf16_t*)p; p += align256(hv_b);    // hW / hv_out (aliased)
    bf16_t* agg    = (bf16_t*)p; p += align256(hv_b);
    bf16_t* xb     = (bf16_t*)p; p += align256(xb_b);    // x in bf16, [N_ATOMS, XKP]
    bf16_t* Wt_i   = (bf16_t*)p; p += align256(wt_b);    // Wi_top^T
    bf16_t* Wt_o1  = (bf16_t*)p; p += align256(wt_b);    // Wo_top^T
    bf16_t* Wt_o2  = (bf16_t*)p; p += align256(wt_b);    // Wo_bot^T
    bf16_t* Wt_a   = (bf16_t*)p; p += align256(wta_b);   // atom_W^T [320][XKP]
    float*  mol    = (float*)p;  p += align256(mol_f);
    float*  ffnh   = (float*)p;  p += align256(mol_f);
    int*    row_ptr= (int*)p;    p += align256(rp_b);
    int*    cntpos = (int*)p;    p += align256(cnt_b);
    int*    eid    = (int*)p;    p += align256(eid_b);

    dim3 blk(256);
    dim3 gM((N_MOLS + BM - 1) / BM, (HIDDEN + BN - 1) / BN);
    dim3 gO((N_MOLS + BM - 1) / BM, (N_LABELS + BN - 1) / BN);
    dim3 gE((N_EDGES + 255) / 256);
    dim3 gW((320 * KPAD + 255) / 256);
    dim3 gWa((320 * XKP + 255) / 256);
    dim3 gX((N_ATOMS * XKP + 255) / 256);
    const int mfx = (N_ATOMS + MT_BM - 1) / MT_BM;              // 782
    dim3 gMF(mfx * MT_NB);                                      // 1D, swizzled in-kernel
    dim3 gGA((N_ATOMS + 15) / 16);                              // 6250, 512-thr blocks

    // ---- one-time per call: converts + CSR ----
    convert_wt<<<gW,  blk, 0, stream>>>(Wi_top, Wt_i,  HIDDEN, HIDDEN, KPAD);
    convert_wt<<<gW,  blk, 0, stream>>>(Wo_top, Wt_o1, HIDDEN, HIDDEN, KPAD);
    convert_wt<<<gW,  blk, 0, stream>>>(Wo_bot, Wt_o2, HIDDEN, HIDDEN, KPAD);
    convert_wt<<<gWa, blk, 0, stream>>>(atom_W, Wt_a,  ATOM_FDIM, HIDDEN, XKP);
    convert_x<<<gX,   blk, 0, stream>>>(x, xb);

    hipMemsetAsync(cntpos, 0, cnt_b, stream);
    csr_hist<<<gE, blk, 0, stream>>>(dst, cntpos, N_EDGES);
    csr_scan<<<dim3(1), dim3(SCAN_T), 0, stream>>>(cntpos, row_ptr);
    hipMemcpyAsync(cntpos, row_ptr, cnt_b, hipMemcpyDeviceToDevice, stream);
    csr_fill<<<gE, blk, 0, stream>>>(dst, cntpos, eid, N_EDGES);

    // 1) h_v = relu(x @ atom_W + atom_b)   [MFMA, K=192]
    gemm_mfma<false, XKP, XKP><<<gMF, blk, 0, stream>>>(
        xb, Wt_a, nullptr, nullptr, atom_b, bufA, N_ATOMS, 1);

    bf16_t* hv_in   = bufA;
    bf16_t* scratch = bufB;   // holds hW, then hv_out
    for (int it = 0; it < DEPTH; ++it) {
        // 2a) hW = h_v @ Wi_top              [MFMA]
        gemm_mfma<false, KPAD, KPAD><<<gMF, blk, 0, stream>>>(
            hv_in, Wt_i, nullptr, nullptr, nullptr, scratch, N_ATOMS, 0);
        // 2b) agg = CSR-gather of relu(hW[src] + ea@WiB)
        gather_agg<<<gGA, dim3(512), 0, stream>>>(
            scratch, ea, src, row_ptr, eid, WiB, agg);
        // 2c) h_v' = relu(h_v @ Wo_top + agg @ Wo_bot + Wo_b)   [MFMA dual]
        gemm_mfma<true, KPAD, KPAD><<<gMF, blk, 0, stream>>>(
            hv_in, Wt_o1, agg, Wt_o2, Wo_b, scratch, N_ATOMS, 1);
        bf16_t* tmp = hv_in; hv_in = scratch; scratch = tmp;
    }

    // 3) mol_repr = segment_sum(h_v, batch)
    hipMemsetAsync(mol, 0, mol_f, stream);
    mol_reduce<<<dim3((N_ATOMS + ATOMS_PER_BLOCK - 1) / ATOMS_PER_BLOCK), dim3(320), 0, stream>>>(
        hv_in, batch, mol, N_ATOMS);

    // 4) ffn [scalar f32]
    gemm_fused<false><<<gM, blk, 0, stream>>>(
        mol, f1W, HIDDEN, f1b, ffnh, N_MOLS, HIDDEN, HIDDEN, 1);
    gemm_fused<false><<<gO, blk, 0, stream>>>(
        ffnh, f2W, HIDDEN, f2b, (float*)d_out, N_MOLS, N_LABELS, N_LABELS, 0);
}

// Round 11
// 1715.398 us; speedup vs baseline: 3.0958x; 1.0097x over previous
//
#include <hip/hip_runtime.h>

#define N_ATOMS 100000
#define N_EDGES 400000
#define N_MOLS  4096
#define ATOM_FDIM 133
#define BOND_FDIM 14
#define HIDDEN 300
#define DEPTH 3
#define N_LABELS 12

#define KPAD 320          // row stride for bf16 activation buffers (and Wt k-stride)
#define XKP  192          // padded K for atom-embed input x (133 -> 192, /64)

#define BM 64
#define BN 64
#define BK 16

typedef unsigned short bf16_t;
typedef __bf16 bf16x8_t __attribute__((ext_vector_type(8)));
typedef float f32x4_t __attribute__((ext_vector_type(4)));

__device__ __forceinline__ float bf2f(bf16_t h) {
    return __uint_as_float(((unsigned int)h) << 16);
}
__device__ __forceinline__ bf16_t f2bf(float f) {
    unsigned int u = __float_as_uint(f);
    u = u + 0x7FFFu + ((u >> 16) & 1u);   // round-to-nearest-even
    return (bf16_t)(u >> 16);
}

// async 256B wave copy: per-lane global src (base + lane*4), wave-uniform LDS dest
typedef const __attribute__((address_space(1))) unsigned int* as1_u32p;
typedef __attribute__((address_space(3))) unsigned int* as3_u32p;
__device__ __forceinline__ void gload4(const void* g, void* l) {
    __builtin_amdgcn_global_load_lds((as1_u32p)g, (as3_u32p)l, 4, 0, 0);
}

// ---------------- scalar GEMM (ffn only: tiny M) ----------------
template<bool CBF>
__global__ __launch_bounds__(256) void gemm_fused(
    const float* __restrict__ A1, const float* __restrict__ W1, int K1,
    const float* __restrict__ bias, void* __restrict__ Cv,
    int M, int N, int ldc, int do_relu)
{
    __shared__ __align__(16) float As[BK][BM + 4];
    __shared__ __align__(16) float Bs[BK][BN];
    const int t  = threadIdx.x;
    const int tx = t & 15;
    const int ty = t >> 4;
    const int m0 = blockIdx.x * BM;
    const int n0 = blockIdx.y * BN;

    const int lr = t >> 2;
    const int lk = (t & 3) * 4;
    const int bk = t >> 4;
    const int bn = (t & 15) * 4;

    float acc[4][4] = {};
    const int K = K1;
    const bool k4 = ((K & 3) == 0);

    for (int k0 = 0; k0 < K; k0 += BK) {
        {
            const int row = m0 + lr;
            const int kbase = k0 + lk;
            float v0 = 0.f, v1 = 0.f, v2 = 0.f, v3 = 0.f;
            if (row < M) {
                const float* ap = A1 + (size_t)row * K;
                if (k4 && (kbase + 3 < K)) {
                    float4 v = *reinterpret_cast<const float4*>(ap + kbase);
                    v0 = v.x; v1 = v.y; v2 = v.z; v3 = v.w;
                } else {
                    if (kbase + 0 < K) v0 = ap[kbase + 0];
                    if (kbase + 1 < K) v1 = ap[kbase + 1];
                    if (kbase + 2 < K) v2 = ap[kbase + 2];
                    if (kbase + 3 < K) v3 = ap[kbase + 3];
                }
            }
            As[lk + 0][lr] = v0;
            As[lk + 1][lr] = v1;
            As[lk + 2][lr] = v2;
            As[lk + 3][lr] = v3;
        }
        {
            const int kk = k0 + bk;
            float v0 = 0.f, v1 = 0.f, v2 = 0.f, v3 = 0.f;
            if (kk < K) {
                const int nbase = n0 + bn;
                if (nbase + 3 < N) {
                    float4 v = *reinterpret_cast<const float4*>(W1 + (size_t)kk * N + nbase);
                    v0 = v.x; v1 = v.y; v2 = v.z; v3 = v.w;
                } else {
                    const float* wp = W1 + (size_t)kk * N;
                    if (nbase + 0 < N) v0 = wp[nbase + 0];
                    if (nbase + 1 < N) v1 = wp[nbase + 1];
                    if (nbase + 2 < N) v2 = wp[nbase + 2];
                    if (nbase + 3 < N) v3 = wp[nbase + 3];
                }
            }
            Bs[bk][bn + 0] = v0;
            Bs[bk][bn + 1] = v1;
            Bs[bk][bn + 2] = v2;
            Bs[bk][bn + 3] = v3;
        }
        __syncthreads();
        #pragma unroll
        for (int k = 0; k < BK; ++k) {
            float4 a = *reinterpret_cast<const float4*>(&As[k][ty * 4]);
            float4 b = *reinterpret_cast<const float4*>(&Bs[k][tx * 4]);
            float av[4] = {a.x, a.y, a.z, a.w};
            float bv[4] = {b.x, b.y, b.z, b.w};
            #pragma unroll
            for (int i = 0; i < 4; ++i)
                #pragma unroll
                for (int j = 0; j < 4; ++j)
                    acc[i][j] = fmaf(av[i], bv[j], acc[i][j]);
        }
        __syncthreads();
    }

    #pragma unroll
    for (int i = 0; i < 4; ++i) {
        const int row = m0 + ty * 4 + i;
        if (row >= M) continue;
        #pragma unroll
        for (int j = 0; j < 4; ++j) {
            const int col = n0 + tx * 4 + j;
            if (col >= N) continue;
            float v = acc[i][j];
            if (bias) v += bias[col];
            if (do_relu) v = fmaxf(v, 0.f);
            if (CBF) ((bf16_t*)Cv)[(size_t)row * ldc + col] = f2bf(v);
            else     ((float*)Cv)[(size_t)row * ldc + col] = v;
        }
    }
}

// ---- weight convert: W f32 [K,N] -> Wt bf16 [320 rows n][lda cols k], zero-pad ----
__global__ void convert_wt(const float* __restrict__ W, bf16_t* __restrict__ Wt,
                           int K, int N, int lda) {
    int idx = blockIdx.x * blockDim.x + threadIdx.x;
    if (idx >= 320 * lda) return;
    int n = idx / lda, k = idx % lda;
    float v = (k < K && n < N) ? W[(size_t)k * N + n] : 0.f;
    Wt[idx] = f2bf(v);
}

// ---- x f32 [N_ATOMS,133] -> bf16 [N_ATOMS, XKP], zero-pad ----
__global__ void convert_x(const float* __restrict__ x, bf16_t* __restrict__ xb) {
    int i = blockIdx.x * blockDim.x + threadIdx.x;
    if (i >= N_ATOMS * XKP) return;
    int r = i / XKP, k = i % XKP;
    xb[i] = f2bf(k < ATOM_FDIM ? x[(size_t)r * ATOM_FDIM + k] : 0.f);
}

// ---------------- MFMA GEMM v2: BK=64, 1D grid + bijective XCD swizzle --------
#define MT_BM 128
#define MT_BN 64
#define MT_BK 64
#define ALD2 72           // LDS row stride in bf16 (64 + 8 pad)
#define MT_NB 5           // N tiles = KPAD / MT_BN

template<bool DUAL, int KMAX, int LDA>
__global__ __launch_bounds__(256) void gemm_mfma(
    const bf16_t* __restrict__ A1, const bf16_t* __restrict__ Wt1,
    const bf16_t* __restrict__ A2, const bf16_t* __restrict__ Wt2,
    const float* __restrict__ bias, bf16_t* __restrict__ C,
    int M, int do_relu)
{
    __shared__ __align__(16) bf16_t Alds[MT_BM][ALD2];   // 18.4 KB
    __shared__ __align__(16) bf16_t Blds[MT_BN][ALD2];   // 9.2 KB
    const int t = threadIdx.x;
    const int lane = t & 63;
    const int wave = t >> 6;
    const int wm = wave >> 1;
    const int wn = wave & 1;

    // bijective chunked XCD swizzle (m204)
    int bid = blockIdx.x;
    {
        const int total = gridDim.x;
        const int q = total >> 3, r = total & 7;
        const int xcd = bid & 7, pos = bid >> 3;
        const int base = (xcd < r) ? xcd * (q + 1) : r * (q + 1) + (xcd - r) * q;
        bid = base + pos;
    }
    const int m0 = (bid / MT_NB) * MT_BM;
    const int n0 = (bid % MT_NB) * MT_BN;

    const int fr = lane & 15;
    const int kg = lane >> 4;

    f32x4_t acc[4][2];
    #pragma unroll
    for (int i = 0; i < 4; ++i)
        #pragma unroll
        for (int j = 0; j < 2; ++j)
            acc[i][j] = f32x4_t{0.f, 0.f, 0.f, 0.f};

    const int NPH = DUAL ? 2 : 1;
    for (int ph = 0; ph < NPH; ++ph) {
        const bf16_t* __restrict__ A  = ph ? A2  : A1;
        const bf16_t* __restrict__ Wt = ph ? Wt2 : Wt1;

        for (int k0 = 0; k0 < KMAX; k0 += MT_BK) {
            #pragma unroll
            for (int cc = 0; cc < 4; ++cc) {
                const int c = t + cc * 256;
                const int row = c >> 3;
                const int cid = c & 7;
                uint4 v = *reinterpret_cast<const uint4*>(
                    A + (size_t)(m0 + row) * LDA + k0 + cid * 8);
                *reinterpret_cast<uint4*>(&Alds[row][cid * 8]) = v;
            }
            #pragma unroll
            for (int cc = 0; cc < 2; ++cc) {
                const int c = t + cc * 256;
                const int row = c >> 3;
                const int cid = c & 7;
                uint4 v = *reinterpret_cast<const uint4*>(
                    Wt + (size_t)(n0 + row) * LDA + k0 + cid * 8);
                *reinterpret_cast<uint4*>(&Blds[row][cid * 8]) = v;
            }
            __syncthreads();

            #pragma unroll
            for (int kk = 0; kk < 2; ++kk) {
                bf16x8_t af[4], bfr[2];
                #pragma unroll
                for (int i = 0; i < 4; ++i)
                    af[i] = *reinterpret_cast<const bf16x8_t*>(
                        &Alds[wm * 64 + i * 16 + fr][kk * 32 + kg * 8]);
                #pragma unroll
                for (int j = 0; j < 2; ++j)
                    bfr[j] = *reinterpret_cast<const bf16x8_t*>(
                        &Blds[wn * 32 + j * 16 + fr][kk * 32 + kg * 8]);
                #pragma unroll
                for (int i = 0; i < 4; ++i)
                    #pragma unroll
                    for (int j = 0; j < 2; ++j)
                        acc[i][j] = __builtin_amdgcn_mfma_f32_16x16x32_bf16(
                            af[i], bfr[j], acc[i][j], 0, 0, 0);
            }
            __syncthreads();
        }
    }

    #pragma unroll
    for (int j = 0; j < 2; ++j) {
        const int col = n0 + wn * 32 + j * 16 + fr;
        if (col >= HIDDEN) continue;
        const float bb = bias ? bias[col] : 0.f;
        #pragma unroll
        for (int i = 0; i < 4; ++i) {
            const int rbase = m0 + wm * 64 + i * 16 + kg * 4;
            #pragma unroll
            for (int q = 0; q < 4; ++q) {
                const int row = rbase + q;
                if (row >= M) continue;
                float v = acc[i][j][q] + bb;
                if (do_relu) v = fmaxf(v, 0.f);
                C[(size_t)row * KPAD + col] = f2bf(v);
            }
        }
    }
}

// ---------------- CSR build over dst ----------------
__global__ void csr_hist(const int* __restrict__ dst, int* __restrict__ cnt, int n) {
    int i = blockIdx.x * blockDim.x + threadIdx.x;
    if (i < n) atomicAdd(&cnt[dst[i]], 1);
}

#define SCAN_T 1024
__global__ __launch_bounds__(SCAN_T) void csr_scan(
    const int* __restrict__ cnt, int* __restrict__ row_ptr) {
    __shared__ int sums[SCAN_T];
    const int t = threadIdx.x;
    const int per = (N_ATOMS + SCAN_T - 1) / SCAN_T;
    const int base = t * per;
    int local = 0;
    for (int i = 0; i < per; ++i) {
        int idx = base + i;
        if (idx < N_ATOMS) local += cnt[idx];
    }
    sums[t] = local;
    __syncthreads();
    for (int off = 1; off < SCAN_T; off <<= 1) {
        int v = (t >= off) ? sums[t - off] : 0;
        __syncthreads();
        if (t >= off) sums[t] += v;
        __syncthreads();
    }
    int prefix = (t == 0) ? 0 : sums[t - 1];
    for (int i = 0; i < per; ++i) {
        int idx = base + i;
        if (idx < N_ATOMS) {
            row_ptr[idx] = prefix;
            prefix += cnt[idx];
        }
    }
    if (t == SCAN_T - 1) row_ptr[N_ATOMS] = prefix;
}

__global__ void csr_fill(const int* __restrict__ dst, int* __restrict__ pos,
                         int* __restrict__ eid, int n) {
    int i = blockIdx.x * blockDim.x + threadIdx.x;
    if (i < n) {
        int p = atomicAdd(&pos[dst[i]], 1);
        eid[p] = i;
    }
}

// ---- presort edges into dst-order: kills eid indirection in the gather ----
__global__ void presort_edges(const int* __restrict__ eid, const int* __restrict__ src,
                              const float* __restrict__ ea,
                              int* __restrict__ src_s, float* __restrict__ ea_s, int n) {
    int i = blockIdx.x * blockDim.x + threadIdx.x;
    if (i >= n) return;
    const int e = eid[i];
    src_s[i] = src[e];
    const float2* s2 = reinterpret_cast<const float2*>(ea + (size_t)e * BOND_FDIM);
    float2* d2 = reinterpret_cast<float2*>(ea_s + (size_t)i * BOND_FDIM);
    #pragma unroll
    for (int q = 0; q < BOND_FDIM / 2; ++q) d2[q] = s2[q];
}

// ---- agg[v] = sum_{e: dst=v} relu(hW[src_e] + ea_e @ WiB), bf16 out ----
// v6: async LDS-DMA pipeline. Wave owns 4 consecutive atoms (contiguous CSR edge
// range). Edges in windows of 4; per window 13 global_load_lds issues (4 edges x
// 3x256B row chunks + 1x256B ea chunk) into a per-wave double buffer; counted
// s_waitcnt vmcnt(13) keeps one window in flight while computing the previous.
// No VGPR cost for in-flight data -> high request concurrency at low regs.
#define WBUF_ELEMS 1664   // 4 edges * 384 bf16 + 128 bf16 (=256B) ea slot

#define GISSUE(W, BUF) { \
    const int bi_ = beg + 4 * (W); \
    _Pragma("unroll") \
    for (int ee_ = 0; ee_ < 4; ++ee_) { \
        int idx_ = bi_ + ee_; if (idx_ > end - 1) idx_ = end - 1; \
        const int s_ = sSrc[idx_ - beg]; \
        const bf16_t* row_ = hW + (size_t)s_ * KPAD; \
        _Pragma("unroll") \
        for (int c_ = 0; c_ < 3; ++c_) \
            gload4(row_ + c_ * 128 + lane * 2, (BUF) + ee_ * 384 + c_ * 128); \
    } \
    gload4(ea_s + (size_t)bi_ * BOND_FDIM + lane, (BUF) + 1536); \
}

__global__ __launch_bounds__(256) void gather_agg(
    const bf16_t* __restrict__ hW, const float* __restrict__ ea_s,
    const int* __restrict__ src_s, const int* __restrict__ row_ptr,
    const float* __restrict__ WiB, bf16_t* __restrict__ agg)
{
    __shared__ __align__(16) float sWiB[BOND_FDIM * KPAD];      // 17.9 KB
    __shared__ __align__(16) bf16_t ebuf[4][2][WBUF_ELEMS];     // 26.6 KB
    __shared__ int sSrcAll[4][128];                             // 2 KB
    const int t = threadIdx.x;
    for (int i = t; i < BOND_FDIM * KPAD; i += 256) {
        const int k = i / KPAD, j = i % KPAD;
        sWiB[i] = (j < HIDDEN) ? WiB[k * HIDDEN + j] : 0.f;
    }
    __syncthreads();

    const int wave = t >> 6;
    const int lane = t & 63;
    const int v0 = blockIdx.x * 16 + wave * 4;
    if (v0 >= N_ATOMS) return;
    const int vN = min(v0 + 4, N_ATOMS);
    const int beg = row_ptr[v0];
    const int b1 = row_ptr[min(v0 + 1, vN)];
    const int b2 = row_ptr[min(v0 + 2, vN)];
    const int b3 = row_ptr[min(v0 + 3, vN)];
    int end = row_ptr[vN];
    const int ne = min(end - beg, 128);   // cap (P(overflow) ~ 0: sum of 4 Poisson(4))
    end = beg + ne;

    int* sSrc = sSrcAll[wave];
    for (int j = lane; j < ne; j += 64) sSrc[j] = src_s[beg + j];
    // compiler inserts the load->ds_write wait; sSrc reads below use lgkmcnt

    float ax[4][3] = {{0.f}}, ay[4][3] = {{0.f}};
    const int nw = (ne + 3) >> 2;
    if (nw > 0) {
        GISSUE(0, &ebuf[wave][0][0])
        for (int w = 0; w < nw; ++w) {
            const bf16_t* buf = &ebuf[wave][w & 1][0];
            if (w + 1 < nw) {
                GISSUE(w + 1, &ebuf[wave][(w + 1) & 1][0])
                asm volatile("s_waitcnt vmcnt(13)" ::: "memory");
            } else {
                asm volatile("s_waitcnt vmcnt(0)" ::: "memory");
            }
            __builtin_amdgcn_sched_barrier(0);
            const int bi = beg + 4 * w;
            #pragma unroll
            for (int ee = 0; ee < 4; ++ee) {
                const int idx = bi + ee;
                if (idx >= end) break;
                const int a = (idx >= b1) + (idx >= b2) + (idx >= b3);
                const float* eaf = reinterpret_cast<const float*>(buf + 1536) + ee * BOND_FDIM;
                float eav[BOND_FDIM];
                #pragma unroll
                for (int k = 0; k < BOND_FDIM; ++k) eav[k] = eaf[k];
                const bool lo = (lane < 32);
                float mx0, my0, mx1, my1, mx2 = 0.f, my2 = 0.f;
                {
                    ushort2 h = *reinterpret_cast<const ushort2*>(buf + ee * 384 + lane * 2);
                    mx0 = bf2f(h.x); my0 = bf2f(h.y);
                }
                {
                    ushort2 h = *reinterpret_cast<const ushort2*>(buf + ee * 384 + 128 + lane * 2);
                    mx1 = bf2f(h.x); my1 = bf2f(h.y);
                }
                if (lo) {
                    ushort2 h = *reinterpret_cast<const ushort2*>(buf + ee * 384 + 256 + lane * 2);
                    mx2 = bf2f(h.x); my2 = bf2f(h.y);
                }
                #pragma unroll
                for (int k = 0; k < BOND_FDIM; ++k) {
                    const float ek = eav[k];
                    float2 w0 = *reinterpret_cast<const float2*>(&sWiB[k * KPAD + 2 * lane]);
                    float2 w1 = *reinterpret_cast<const float2*>(&sWiB[k * KPAD + 128 + 2 * lane]);
                    mx0 = fmaf(ek, w0.x, mx0); my0 = fmaf(ek, w0.y, my0);
                    mx1 = fmaf(ek, w1.x, mx1); my1 = fmaf(ek, w1.y, my1);
                    if (lo) {
                        float2 w2 = *reinterpret_cast<const float2*>(&sWiB[k * KPAD + 256 + 2 * lane]);
                        mx2 = fmaf(ek, w2.x, mx2); my2 = fmaf(ek, w2.y, my2);
                    }
                }
                const float r0x = fmaxf(mx0, 0.f), r0y = fmaxf(my0, 0.f);
                const float r1x = fmaxf(mx1, 0.f), r1y = fmaxf(my1, 0.f);
                const float r2x = fmaxf(mx2, 0.f), r2y = fmaxf(my2, 0.f);
                #pragma unroll
                for (int q = 0; q < 4; ++q) {   // static acc indexing (rule #20)
                    const bool m = (a == q);
                    ax[q][0] += m ? r0x : 0.f; ay[q][0] += m ? r0y : 0.f;
                    ax[q][1] += m ? r1x : 0.f; ay[q][1] += m ? r1y : 0.f;
                    ax[q][2] += m ? r2x : 0.f; ay[q][2] += m ? r2y : 0.f;
                }
            }
        }
    }

    #pragma unroll
    for (int q = 0; q < 4; ++q) {
        const int v = v0 + q;
        if (v >= vN) break;
        bf16_t* __restrict__ arow = agg + (size_t)v * KPAD;
        { ushort2 o; o.x = f2bf(ax[q][0]); o.y = f2bf(ay[q][0]);
          *reinterpret_cast<ushort2*>(arow + 2 * lane) = o; }
        { ushort2 o; o.x = f2bf(ax[q][1]); o.y = f2bf(ay[q][1]);
          *reinterpret_cast<ushort2*>(arow + 128 + 2 * lane) = o; }
        if (lane < 32) {
          ushort2 o; o.x = f2bf(ax[q][2]); o.y = f2bf(ay[q][2]);
          *reinterpret_cast<ushort2*>(arow + 256 + 2 * lane) = o; }
    }
}

// Segment-sum of bf16 h_v (stride KPAD) into fp32 mol_repr (batch sorted).
#define ATOMS_PER_BLOCK 32
__global__ __launch_bounds__(320) void mol_reduce(
    const bf16_t* __restrict__ hv, const int* __restrict__ batch,
    float* __restrict__ mol, int n_atoms)
{
    const int j = threadIdx.x;
    if (j >= HIDDEN) return;
    const int a0 = blockIdx.x * ATOMS_PER_BLOCK;
    const int aend = min(a0 + ATOMS_PER_BLOCK, n_atoms);
    float acc = 0.f;
    int cur = batch[a0];
    for (int a = a0; a < aend; ++a) {
        const int b = batch[a];
        if (b != cur) {
            atomicAdd(&mol[(size_t)cur * HIDDEN + j], acc);
            acc = 0.f;
            cur = b;
        }
        acc += bf2f(hv[(size_t)a * KPAD + j]);
    }
    atomicAdd(&mol[(size_t)cur * HIDDEN + j], acc);
}

__global__ void fill_const(float* p, int n, float v) {
    int i = blockIdx.x * blockDim.x + threadIdx.x;
    if (i < n) p[i] = v;
}

static inline size_t align256(size_t x) { return (x + 255) & ~(size_t)255; }

extern "C" void kernel_launch(void* const* d_in, const int* in_sizes, int n_in,
                              void* d_out, int out_size, void* d_ws, size_t ws_size,
                              hipStream_t stream) {
    const float* x       = (const float*)d_in[0];
    const int*   ei      = (const int*)  d_in[1];
    const float* ea      = (const float*)d_in[2];
    const int*   batch   = (const int*)  d_in[3];
    const float* atom_W  = (const float*)d_in[4];
    const float* atom_b  = (const float*)d_in[5];
    // d_in[6] bond_W, d_in[7] bond_b, d_in[9] Wh: dead code
    const float* Wi      = (const float*)d_in[8];    // [314,300]
    const float* Wo      = (const float*)d_in[10];   // [600,300]
    const float* Wo_b    = (const float*)d_in[11];
    const float* f1W     = (const float*)d_in[12];
    const float* f1b     = (const float*)d_in[13];
    const float* f2W     = (const float*)d_in[14];
    const float* f2b     = (const float*)d_in[15];

    const int* src = ei;            // edge_index[0]
    const int* dst = ei + N_EDGES;  // edge_index[1]

    const float* Wi_top = Wi;                            // [300,300]
    const float* WiB    = Wi + (size_t)HIDDEN * HIDDEN;  // [14,300]
    const float* Wo_top = Wo;                            // [300,300]
    const float* Wo_bot = Wo + (size_t)HIDDEN * HIDDEN;  // [300,300]

    // ---- workspace ----
    const size_t hv_b   = (size_t)N_ATOMS * KPAD * sizeof(bf16_t);  // 64 MB
    const size_t xb_b   = (size_t)N_ATOMS * XKP  * sizeof(bf16_t);  // 38.4 MB
    const size_t wt_b   = (size_t)320 * KPAD * sizeof(bf16_t);      // 200 KB
    const size_t wta_b  = (size_t)320 * XKP  * sizeof(bf16_t);      // 120 KB
    const size_t mol_f  = (size_t)N_MOLS * HIDDEN * sizeof(float);  // 4.9 MB
    const size_t rp_b   = (size_t)(N_ATOMS + 1) * sizeof(int);
    const size_t cnt_b  = (size_t)N_ATOMS * sizeof(int);
    const size_t eid_b  = (size_t)N_EDGES * sizeof(int);
    const size_t needed = 3 * align256(hv_b) + align256(xb_b)
                        + 3 * align256(wt_b) + align256(wta_b)
                        + 2 * align256(mol_f)
                        + align256(rp_b) + align256(cnt_b) + align256(eid_b)
                        + 65536;   // slack for benign OOB-row staging reads
    if (ws_size < needed) {
        fill_const<<<dim3((out_size + 255) / 256), dim3(256), 0, stream>>>(
            (float*)d_out, out_size, 1.0e6f);   // canary: ws too small
        return;
    }
    char* p = (char*)d_ws;
    bf16_t* bufA   = (bf16_t*)p; p += align256(hv_b);    // hv ping
    bf16_t* bufB   = (bf16_t*)p; p += align256(hv_b);    // hW / hv_out (aliased)
    bf16_t* agg    = (bf16_t*)p; p += align256(hv_b);
    bf16_t* xb     = (bf16_t*)p; p += align256(xb_b);    // x bf16; later ea_s/src_s
    bf16_t* Wt_i   = (bf16_t*)p; p += align256(wt_b);    // Wi_top^T
    bf16_t* Wt_o1  = (bf16_t*)p; p += align256(wt_b);    // Wo_top^T
    bf16_t* Wt_o2  = (bf16_t*)p; p += align256(wt_b);    // Wo_bot^T
    bf16_t* Wt_a   = (bf16_t*)p; p += align256(wta_b);   // atom_W^T [320][XKP]
    float*  mol    = (float*)p;  p += align256(mol_f);
    float*  ffnh   = (float*)p;  p += align256(mol_f);
    int*    row_ptr= (int*)p;    p += align256(rp_b);
    int*    cntpos = (int*)p;    p += align256(cnt_b);
    int*    eid    = (int*)p;    p += align256(eid_b);

    // dst-sorted edge data lives in the xb region (xb is dead after the embed GEMM)
    float* ea_s  = (float*)xb;                                   // 22.4 MB + pad
    int*   src_s = (int*)((char*)xb + 23u * 1024 * 1024);        // 1.6 MB

    dim3 blk(256);
    dim3 gM((N_MOLS + BM - 1) / BM, (HIDDEN + BN - 1) / BN);
    dim3 gO((N_MOLS + BM - 1) / BM, (N_LABELS + BN - 1) / BN);
    dim3 gE((N_EDGES + 255) / 256);
    dim3 gW((320 * KPAD + 255) / 256);
    dim3 gWa((320 * XKP + 255) / 256);
    dim3 gX((N_ATOMS * XKP + 255) / 256);
    const int mfx = (N_ATOMS + MT_BM - 1) / MT_BM;              // 782
    dim3 gMF(mfx * MT_NB);                                      // 1D, swizzled in-kernel
    dim3 gGA((N_ATOMS + 15) / 16);                              // 6250

    // ---- one-time per call: converts + CSR ----
    convert_wt<<<gW,  blk, 0, stream>>>(Wi_top, Wt_i,  HIDDEN, HIDDEN, KPAD);
    convert_wt<<<gW,  blk, 0, stream>>>(Wo_top, Wt_o1, HIDDEN, HIDDEN, KPAD);
    convert_wt<<<gW,  blk, 0, stream>>>(Wo_bot, Wt_o2, HIDDEN, HIDDEN, KPAD);
    convert_wt<<<gWa, blk, 0, stream>>>(atom_W, Wt_a,  ATOM_FDIM, HIDDEN, XKP);
    convert_x<<<gX,   blk, 0, stream>>>(x, xb);

    hipMemsetAsync(cntpos, 0, cnt_b, stream);
    csr_hist<<<gE, blk, 0, stream>>>(dst, cntpos, N_EDGES);
    csr_scan<<<dim3(1), dim3(SCAN_T), 0, stream>>>(cntpos, row_ptr);
    hipMemcpyAsync(cntpos, row_ptr, cnt_b, hipMemcpyDeviceToDevice, stream);
    csr_fill<<<gE, blk, 0, stream>>>(dst, cntpos, eid, N_EDGES);

    // 1) h_v = relu(x @ atom_W + atom_b)   [MFMA, K=192] — consumes xb
    gemm_mfma<false, XKP, XKP><<<gMF, blk, 0, stream>>>(
        xb, Wt_a, nullptr, nullptr, atom_b, bufA, N_ATOMS, 1);

    // presort edge data into dst-order (overwrites dead xb region)
    presort_edges<<<gE, blk, 0, stream>>>(eid, src, ea, src_s, ea_s, N_EDGES);

    bf16_t* hv_in   = bufA;
    bf16_t* scratch = bufB;   // holds hW, then hv_out
    for (int it = 0; it < DEPTH; ++it) {
        // 2a) hW = h_v @ Wi_top              [MFMA]
        gemm_mfma<false, KPAD, KPAD><<<gMF, blk, 0, stream>>>(
            hv_in, Wt_i, nullptr, nullptr, nullptr, scratch, N_ATOMS, 0);
        // 2b) agg = CSR-gather of relu(hW[src] + ea@WiB)   [async LDS-DMA v6]
        gather_agg<<<gGA, blk, 0, stream>>>(
            scratch, ea_s, src_s, row_ptr, WiB, agg);
        // 2c) h_v' = relu(h_v @ Wo_top + agg @ Wo_bot + Wo_b)   [MFMA dual]
        gemm_mfma<true, KPAD, KPAD><<<gMF, blk, 0, stream>>>(
            hv_in, Wt_o1, agg, Wt_o2, Wo_b, scratch, N_ATOMS, 1);
        bf16_t* tmp = hv_in; hv_in = scratch; scratch = tmp;
    }

    // 3) mol_repr = segment_sum(h_v, batch)
    hipMemsetAsync(mol, 0, mol_f, stream);
    mol_reduce<<<dim3((N_ATOMS + ATOMS_PER_BLOCK - 1) / ATOMS_PER_BLOCK), dim3(320), 0, stream>>>(
        hv_in, batch, mol, N_ATOMS);

    // 4) ffn [scalar f32]
    gemm_fused<false><<<gM, blk, 0, stream>>>(
        mol, f1W, HIDDEN, f1b, ffnh, N_MOLS, HIDDEN, HIDDEN, 1);
    gemm_fused<false><<<gO, blk, 0, stream>>>(
        ffnh, f2W, HIDDEN, f2b, (float*)d_out, N_MOLS, N_LABELS, N_LABELS, 0);
}